// Round 7
// baseline (1507.370 us; speedup 1.0000x reference)
//
#include <hip/hip_runtime.h>
#include <stdint.h>
#include <stddef.h>

typedef __attribute__((ext_vector_type(8))) short short8;
typedef __attribute__((ext_vector_type(4))) float float4v;

#define T_SEQ 2048
#define D_MODEL 1024
#define NH 16
#define HD 64

static __device__ __forceinline__ unsigned short f2bf(float f) {
  unsigned u = __builtin_bit_cast(unsigned, f);
  u += 0x7fffu + ((u >> 16) & 1u);
  return (unsigned short)(u >> 16);
}
static __device__ __forceinline__ float bf2f(unsigned short h) {
  unsigned u = ((unsigned)h) << 16;
  return __builtin_bit_cast(float, u);
}
static __device__ __forceinline__ float4v mfma16(short8 a, short8 b, float4v c) {
  return __builtin_amdgcn_mfma_f32_16x16x32_bf16(a, b, c, 0, 0, 0);
}
// fp32 -> 3 bf16 terms (sum reproduces f to ~2^-27 rel)
static __device__ __forceinline__ void split3(float f, unsigned short& h0,
                                              unsigned short& h1, unsigned short& h2) {
  h0 = f2bf(f);
  float r1 = f - bf2f(h0);
  h1 = f2bf(r1);
  float r2 = r1 - bf2f(h1);
  h2 = f2bf(r2);
}
// fp32 -> 2 bf16 terms (~2^-18 rel)
static __device__ __forceinline__ void split2(float f, unsigned short& h0, unsigned short& h1) {
  h0 = f2bf(f);
  h1 = f2bf(f - bf2f(h0));
}

// async global->LDS, 16 B per lane (global_load_lds_dwordx4); guarded fallback
static __device__ __forceinline__ void stage16(const unsigned short* g, unsigned short* l) {
#if __has_builtin(__builtin_amdgcn_global_load_lds)
  __builtin_amdgcn_global_load_lds(
      (const __attribute__((address_space(1))) unsigned int*)g,
      (__attribute__((address_space(3))) unsigned int*)l, 16, 0, 0);
#else
  *(short8*)l = *(const short8*)g;
#endif
}

// ---------------- eta tables ----------------
__global__ void eta_kernel(const float* theta, float* E, float* Einv) {
  int i = blockIdx.x * blockDim.x + threadIdx.x;
  if (i >= T_SEQ) return;
  float th = theta[0];
  float h = log1pf(expf(th));            // softplus
  float t = 1.0f + h * (float)i;         // T0 = 1
  float eta = 3.0f * logf(t);            // C_LOG = 3
  eta = fminf(fmaxf(eta, -50.0f), 50.0f);
  E[i] = expf(eta);
  Einv[i] = expf(-eta);
}

// ---------------- LayerNorm (fp32 in) -> 3-way split y ----------------
__global__ __launch_bounds__(256) void ln_kernel(const float* x, const float* wgt,
                          unsigned short* y0, unsigned short* y1, unsigned short* y2) {
  int row = blockIdx.x;
  int tid = threadIdx.x;
  const float* xr = x + (size_t)row * D_MODEL;
  float v[4];
  float sum = 0.f, ssq = 0.f;
  for (int it = 0; it < 4; ++it) {
    float f = xr[tid + 256 * it];
    v[it] = f;
    sum += f; ssq += f * f;
  }
  for (int off = 32; off >= 1; off >>= 1) {
    sum += __shfl_xor(sum, off, 64);
    ssq += __shfl_xor(ssq, off, 64);
  }
  __shared__ float rs[4], rq[4];
  int w = tid >> 6;
  if ((tid & 63) == 0) { rs[w] = sum; rq[w] = ssq; }
  __syncthreads();
  sum = rs[0] + rs[1] + rs[2] + rs[3];
  ssq = rq[0] + rq[1] + rq[2] + rq[3];
  float mu = sum * (1.0f / D_MODEL);
  float var = ssq * (1.0f / D_MODEL) - mu * mu;
  float rstd = rsqrtf(var + 1e-5f);
  for (int it = 0; it < 4; ++it) {
    int d = tid + 256 * it;
    float y = (v[it] - mu) * rstd * wgt[d];
    unsigned short h0, h1, h2;
    split3(y, h0, h1, h2);
    size_t o = (size_t)row * D_MODEL + d;
    y0[o] = h0; y1[o] = h1; y2[o] = h2;
  }
}

// ---------------- attn_w (fp32) -> split3; W2 only for rows < 2048 (Q,K) ----------------
__global__ __launch_bounds__(256) void conv_w3(const float* src, unsigned short* W0,
                                               unsigned short* W1, unsigned short* W2) {
  size_t base = ((size_t)blockIdx.x * 256 + threadIdx.x) * 8;
  int row = (int)(base >> 10);
  short8 a, b, c;
  for (int j = 0; j < 8; ++j) {
    unsigned short h0, h1, h2;
    split3(src[base + j], h0, h1, h2);
    a[j] = (short)h0; b[j] = (short)h1; c[j] = (short)h2;
  }
  *(short8*)(W0 + base) = a;
  *(short8*)(W1 + base) = b;
  if (row < 2048) *(short8*)(W2 + base) = c;
}

// ---------------- proj_w (fp32) -> split2 ----------------
__global__ __launch_bounds__(256) void conv_pw(const float* src, unsigned short* P0,
                                               unsigned short* P1) {
  size_t base = ((size_t)blockIdx.x * 256 + threadIdx.x) * 8;
  short8 a, b;
  for (int j = 0; j < 8; ++j) {
    unsigned short h0, h1;
    split2(src[base + j], h0, h1);
    a[j] = (short)h0; b[j] = (short)h1;
  }
  *(short8*)(P0 + base) = a;
  *(short8*)(P1 + base) = b;
}

// ---------------- Q,K GEMM: LDS-staged 128x128 tile, 6-term split ----------------
// Epilogue prescales: Q *= E[t]*0.125*log2(e)  (softmax in base-2 domain),
//                     K *= Einv[t], then split3 to bf16.
__global__ __launch_bounds__(256) void qkv_qk(
    const unsigned short* y0, const unsigned short* y1, const unsigned short* y2,
    const unsigned short* W0, const unsigned short* W1, const unsigned short* W2,
    const float* E, const float* Einv,
    float* Qf, unsigned short* K0, unsigned short* K1, unsigned short* K2) {
  __shared__ unsigned short As[3][128 * 32];   // 8 KB each
  __shared__ unsigned short Bs[3][128 * 32];
  int tid = threadIdx.x;
  int w = tid >> 6, lane = tid & 63, q4 = lane >> 4, ln = lane & 15;
  int wr = w >> 1, wc = w & 1;
  int n0g = blockIdx.x * 128;   // 0..2047 (Q then K region)
  int m0 = blockIdx.y * 128;
  const unsigned short* Asrc[3] = {y0, y1, y2};
  const unsigned short* Bsrc[3] = {W0, W1, W2};

  float4v zero = {0.f, 0.f, 0.f, 0.f};
  float4v acc[4][4];
  for (int mt = 0; mt < 4; ++mt)
    for (int ct = 0; ct < 4; ++ct) acc[mt][ct] = zero;

  int srow = tid >> 2;          // 0..63
  int kpart = tid & 3;          // 0..3
  unsigned lds_off = (unsigned)tid * 16;   // bytes

  for (int k0 = 0; k0 < D_MODEL; k0 += 32) {
    __syncthreads();   // prev round's ds_reads done before overwrite
    for (int i = 0; i < 2; ++i) {
      size_t arow = (size_t)(m0 + srow + i * 64) * D_MODEL + k0 + kpart * 8;
      size_t brow = (size_t)(n0g + srow + i * 64) * D_MODEL + k0 + kpart * 8;
      for (int s = 0; s < 3; ++s) {
        stage16(Asrc[s] + arow, (unsigned short*)((char*)As[s] + lds_off + i * 4096));
        stage16(Bsrc[s] + brow, (unsigned short*)((char*)Bs[s] + lds_off + i * 4096));
      }
    }
    __syncthreads();   // staging visible

    short8 af[4][3];
    for (int mt = 0; mt < 4; ++mt)
      for (int s = 0; s < 3; ++s)
        af[mt][s] = *(const short8*)&As[s][(wr * 64 + mt * 16 + ln) * 32 + q4 * 8];
    for (int ct = 0; ct < 4; ++ct) {
      int brow = (wc * 64 + ct * 16 + ln) * 32 + q4 * 8;
      short8 b0 = *(const short8*)&Bs[0][brow];
      short8 b1 = *(const short8*)&Bs[1][brow];
      short8 b2 = *(const short8*)&Bs[2][brow];
      for (int mt = 0; mt < 4; ++mt) {
        float4v a = acc[mt][ct];
        a = mfma16(af[mt][0], b0, a);
        a = mfma16(af[mt][1], b0, a);
        a = mfma16(af[mt][0], b1, a);
        a = mfma16(af[mt][1], b1, a);
        a = mfma16(af[mt][0], b2, a);
        a = mfma16(af[mt][2], b0, a);
        acc[mt][ct] = a;
      }
    }
  }

  int region = n0g >> 10;            // 0=Q 1=K
  for (int mt = 0; mt < 4; ++mt)
    for (int ct = 0; ct < 4; ++ct)
      for (int r = 0; r < 4; ++r) {
        int gm = m0 + wr * 64 + mt * 16 + q4 * 4 + r;
        int col = n0g + wc * 64 + ct * 16 + ln;
        int bi = gm >> 11, t = gm & 2047;
        int h = (col & 1023) >> 6, d = col & 63;
        size_t o = ((size_t)(bi * NH + h) * T_SEQ + t) * HD + d;
        float val = acc[mt][ct][r];
        if (region == 0) {
          Qf[o] = val * (E[t] * (0.125f * 1.44269504f));
        } else {
          unsigned short h0, h1, h2;
          split3(val * Einv[t], h0, h1, h2);
          K0[o] = h0; K1[o] = h1; K2[o] = h2;
        }
      }
}

// ---------------- V GEMM: LDS-staged, 3-term, bf16-out transposed [b,h,d,t] ----------------
__global__ __launch_bounds__(256) void qkv_v(
    const unsigned short* y0, const unsigned short* y1,
    const unsigned short* W0, const unsigned short* W1, unsigned short* VbT) {
  __shared__ unsigned short As[2][128 * 32];
  __shared__ unsigned short Bs[2][128 * 32];
  int tid = threadIdx.x;
  int w = tid >> 6, lane = tid & 63, q4 = lane >> 4, ln = lane & 15;
  int wr = w >> 1, wc = w & 1;
  int n0g = blockIdx.x * 128;        // 0..1023 within V region
  int m0 = blockIdx.y * 128;
  const unsigned short* Asrc[2] = {y0, y1};
  const unsigned short* Bsrc[2] = {W0, W1};

  float4v zero = {0.f, 0.f, 0.f, 0.f};
  float4v acc[4][4];
  for (int mt = 0; mt < 4; ++mt)
    for (int ct = 0; ct < 4; ++ct) acc[mt][ct] = zero;

  int srow = tid >> 2, kpart = tid & 3;
  unsigned lds_off = (unsigned)tid * 16;

  for (int k0 = 0; k0 < D_MODEL; k0 += 32) {
    __syncthreads();
    for (int i = 0; i < 2; ++i) {
      size_t arow = (size_t)(m0 + srow + i * 64) * D_MODEL + k0 + kpart * 8;
      size_t brow = (size_t)(2048 + n0g + srow + i * 64) * D_MODEL + k0 + kpart * 8;
      for (int s = 0; s < 2; ++s) {
        stage16(Asrc[s] + arow, (unsigned short*)((char*)As[s] + lds_off + i * 4096));
        stage16(Bsrc[s] + brow, (unsigned short*)((char*)Bs[s] + lds_off + i * 4096));
      }
    }
    __syncthreads();

    short8 af[4][2];
    for (int mt = 0; mt < 4; ++mt)
      for (int s = 0; s < 2; ++s)
        af[mt][s] = *(const short8*)&As[s][(wr * 64 + mt * 16 + ln) * 32 + q4 * 8];
    for (int ct = 0; ct < 4; ++ct) {
      int brow = (wc * 64 + ct * 16 + ln) * 32 + q4 * 8;
      short8 b0 = *(const short8*)&Bs[0][brow];
      short8 b1 = *(const short8*)&Bs[1][brow];
      for (int mt = 0; mt < 4; ++mt) {
        float4v a = acc[mt][ct];
        a = mfma16(af[mt][0], b0, a);
        a = mfma16(af[mt][1], b0, a);
        a = mfma16(af[mt][0], b1, a);
        acc[mt][ct] = a;
      }
    }
  }

  for (int mt = 0; mt < 4; ++mt)
    for (int ct = 0; ct < 4; ++ct) {
      int tb = m0 + wr * 64 + mt * 16 + q4 * 4;   // 4 consecutive t
      int bi = tb >> 11, t = tb & 2047;
      int col = n0g + wc * 64 + ct * 16 + ln;
      int h = col >> 6, d = col & 63;
      unsigned short tmp[4];
      for (int r = 0; r < 4; ++r) tmp[r] = f2bf(acc[mt][ct][r]);
      *(uint64_t*)(VbT + ((size_t)((bi * NH + h) * HD + d) * T_SEQ + t)) =
          *(const uint64_t*)tmp;
    }
}

// ---------------- fused causal attention ----------------
// 8 waves/block: waves 0-3 even jt, 4-7 odd jt of the same q-tiles (balanced +-1);
// jt loop is barrier-free; one LDS merge per q-tile. Q/K pre-scaled (base-2 domain).
__global__ __launch_bounds__(512, 4) void attn_kernel(
    const float* Qf, const unsigned short* K0, const unsigned short* K1,
    const unsigned short* K2, const unsigned short* VbT,
    unsigned short* Ob0, unsigned short* Ob1) {
  __shared__ unsigned short Plds[8][16][72];   // per-wave P tile, padded
  __shared__ float OM[4][16][68];              // odd-parity partial O
  __shared__ float LM[4][16];                  // odd-parity partial l
  __shared__ float MM[8][16];                  // per-wave row maxes
  int tid = threadIdx.x;
  int w = tid >> 6, lane = tid & 63, q4 = lane >> 4, ln = lane & 15;
  int wq = w & 3;        // q-subtile (16 rows)
  int par = w >> 2;      // jt parity
  int px = blockIdx.x;   // 0..15 -> pair (px, 31-px)
  int bh = blockIdx.y;
  const float* Qb = Qf + (size_t)bh * T_SEQ * HD;
  size_t kbase = (size_t)bh * T_SEQ * HD;
  const unsigned short* Vb = VbT + (size_t)bh * HD * T_SEQ;
  int b = bh >> 4, hh = bh & 15;
  float4v zero = {0.f, 0.f, 0.f, 0.f};
  short8 ones;
  for (int j = 0; j < 8; ++j) ones[j] = (short)(unsigned short)0x3F80;  // bf16 1.0

  for (int half = 0; half < 2; ++half) {
    int qt = half ? (31 - px) : px;
    int q0 = qt * 64;
    int ibase = q0 + wq * 16;

    // Q fragments (pre-scaled by E_i*0.125*log2e), 3-way split once per tile
    short8 qa[2][3];
    {
      const float* qp = Qb + (size_t)(ibase + ln) * HD;
      for (int ks = 0; ks < 2; ++ks) {
        float f[8];
        *(float4v*)&f[0] = *(const float4v*)(qp + ks * 32 + q4 * 8);
        *(float4v*)&f[4] = *(const float4v*)(qp + ks * 32 + q4 * 8 + 4);
        for (int j = 0; j < 8; ++j) {
          unsigned short h0, h1, h2;
          split3(f[j], h0, h1, h2);
          qa[ks][0][j] = (short)h0; qa[ks][1][j] = (short)h1; qa[ks][2][j] = (short)h2;
        }
      }
    }

    float m_r[4] = {-3e38f, -3e38f, -3e38f, -3e38f};
    float4v lacc = zero;
    float4v oacc[4];
    for (int c = 0; c < 4; ++c) oacc[c] = zero;

    for (int jt = par; jt <= qt; jt += 2) {
      int j0 = jt * 64;
      bool diag = (jt == qt);
      float p[4][4];   // [c][r]: base-2 logits, then probabilities
      for (int c = 0; c < 4; ++c) {
        int jrow = j0 + c * 16 + ln;
        size_t ko = kbase + (size_t)jrow * HD;
        float4v s = zero;
        for (int ks = 0; ks < 2; ++ks) {
          size_t off = ko + ks * 32 + q4 * 8;
          short8 k0v = *(const short8*)(K0 + off);
          short8 k1v = *(const short8*)(K1 + off);
          short8 k2v = *(const short8*)(K2 + off);
          s = mfma16(qa[ks][0], k0v, s);
          s = mfma16(qa[ks][1], k0v, s);
          s = mfma16(qa[ks][0], k1v, s);
          s = mfma16(qa[ks][1], k1v, s);
          s = mfma16(qa[ks][0], k2v, s);
          s = mfma16(qa[ks][2], k0v, s);
        }
        for (int r = 0; r < 4; ++r) {
          float l = s[r];
          if (diag && jrow > ibase + q4 * 4 + r) l = -3e38f;   // causal mask
          p[c][r] = l;
        }
      }
      float alpha[4], mnew[4];
      for (int r = 0; r < 4; ++r) {
        float tm = fmaxf(fmaxf(p[0][r], p[1][r]), fmaxf(p[2][r], p[3][r]));
        for (int off = 8; off >= 1; off >>= 1) tm = fmaxf(tm, __shfl_xor(tm, off, 16));
        mnew[r] = fmaxf(m_r[r], tm);
        alpha[r] = exp2f(m_r[r] - mnew[r]);
        m_r[r] = mnew[r];
      }
      for (int c = 0; c < 4; ++c)
        for (int r = 0; r < 4; ++r)
          p[c][r] = exp2f(p[c][r] - mnew[r]);
      for (int c = 0; c < 4; ++c)
        for (int r = 0; r < 4; ++r) oacc[c][r] *= alpha[r];
      for (int r = 0; r < 4; ++r) lacc[r] *= alpha[r];

      __asm__ __volatile__("" ::: "memory");
      for (int c = 0; c < 4; ++c)
        for (int r = 0; r < 4; ++r)
          Plds[w][q4 * 4 + r][c * 16 + ln] = f2bf(p[c][r]);
      __asm__ __volatile__("" ::: "memory");

      // P·V + row-sum l via ones-column MFMA
      for (int ks = 0; ks < 2; ++ks) {
        short8 pa = *(const short8*)&Plds[w][ln][ks * 32 + q4 * 8];
        int jb = j0 + ks * 32 + q4 * 8;
        for (int c = 0; c < 4; ++c) {
          short8 vb = *(const short8*)(Vb + (size_t)(c * 16 + ln) * T_SEQ + jb);
          oacc[c] = mfma16(pa, vb, oacc[c]);
        }
        lacc = mfma16(pa, ones, lacc);
      }
      __asm__ __volatile__("" ::: "memory");
    }

    // ---- parity merge through LDS ----
    if (ln == 0)
      for (int r = 0; r < 4; ++r) MM[w][q4 * 4 + r] = m_r[r];
    __syncthreads();
    float ar[4];
    for (int r = 0; r < 4; ++r) {
      float mo = MM[w ^ 4][q4 * 4 + r];
      float mm = fmaxf(m_r[r], mo);
      ar[r] = exp2f(m_r[r] - mm);
    }
    for (int c = 0; c < 4; ++c)
      for (int r = 0; r < 4; ++r) oacc[c][r] *= ar[r];
    for (int r = 0; r < 4; ++r) lacc[r] *= ar[r];
    if (par == 1) {
      for (int c = 0; c < 4; ++c)
        for (int r = 0; r < 4; ++r) OM[wq][q4 * 4 + r][c * 16 + ln] = oacc[c][r];
      if (ln == 0)
        for (int r = 0; r < 4; ++r) LM[wq][q4 * 4 + r] = lacc[r];
    }
    __syncthreads();
    if (par == 0) {
      float lt[4];
      for (int r = 0; r < 4; ++r) lt[r] = lacc[r] + LM[wq][q4 * 4 + r];
      for (int c = 0; c < 4; ++c)
        for (int r = 0; r < 4; ++r) {
          int i = ibase + q4 * 4 + r;
          float val = (oacc[c][r] + OM[wq][q4 * 4 + r][c * 16 + ln]) / lt[r];
          unsigned short h0, h1;
          split2(val, h0, h1);
          size_t o = ((size_t)(b * T_SEQ + i)) * D_MODEL + hh * 64 + c * 16 + ln;
          Ob0[o] = h0; Ob1[o] = h1;
        }
    }
    __syncthreads();   // protect OM/LM/MM reuse by next half
  }
}

// ---------------- output projection: LDS-staged, 3-term, fp32 out ----------------
__global__ __launch_bounds__(256) void proj_gemm(
    const unsigned short* A0, const unsigned short* A1,
    const unsigned short* P0, const unsigned short* P1, float* out) {
  __shared__ unsigned short As[2][128 * 32];
  __shared__ unsigned short Bs[2][128 * 32];
  int tid = threadIdx.x;
  int w = tid >> 6, lane = tid & 63, q4 = lane >> 4, ln = lane & 15;
  int wr = w >> 1, wc = w & 1;
  int n0g = blockIdx.x * 128;
  int m0 = blockIdx.y * 128;
  const unsigned short* Asrc[2] = {A0, A1};
  const unsigned short* Bsrc[2] = {P0, P1};

  float4v zero = {0.f, 0.f, 0.f, 0.f};
  float4v acc[4][4];
  for (int mt = 0; mt < 4; ++mt)
    for (int ct = 0; ct < 4; ++ct) acc[mt][ct] = zero;

  int srow = tid >> 2, kpart = tid & 3;
  unsigned lds_off = (unsigned)tid * 16;

  for (int k0 = 0; k0 < D_MODEL; k0 += 32) {
    __syncthreads();
    for (int i = 0; i < 2; ++i) {
      size_t arow = (size_t)(m0 + srow + i * 64) * D_MODEL + k0 + kpart * 8;
      size_t brow = (size_t)(n0g + srow + i * 64) * D_MODEL + k0 + kpart * 8;
      for (int s = 0; s < 2; ++s) {
        stage16(Asrc[s] + arow, (unsigned short*)((char*)As[s] + lds_off + i * 4096));
        stage16(Bsrc[s] + brow, (unsigned short*)((char*)Bs[s] + lds_off + i * 4096));
      }
    }
    __syncthreads();

    short8 af[4][2];
    for (int mt = 0; mt < 4; ++mt)
      for (int s = 0; s < 2; ++s)
        af[mt][s] = *(const short8*)&As[s][(wr * 64 + mt * 16 + ln) * 32 + q4 * 8];
    for (int ct = 0; ct < 4; ++ct) {
      int brow = (wc * 64 + ct * 16 + ln) * 32 + q4 * 8;
      short8 b0 = *(const short8*)&Bs[0][brow];
      short8 b1 = *(const short8*)&Bs[1][brow];
      for (int mt = 0; mt < 4; ++mt) {
        float4v a = acc[mt][ct];
        a = mfma16(af[mt][0], b0, a);
        a = mfma16(af[mt][1], b0, a);
        a = mfma16(af[mt][0], b1, a);
        acc[mt][ct] = a;
      }
    }
  }

  for (int mt = 0; mt < 4; ++mt)
    for (int ct = 0; ct < 4; ++ct)
      for (int r = 0; r < 4; ++r) {
        int gm = m0 + wr * 64 + mt * 16 + q4 * 4 + r;
        int col = n0g + wc * 64 + ct * 16 + ln;
        out[(size_t)gm * D_MODEL + col] = acc[mt][ct][r];
      }
}

extern "C" void kernel_launch(void* const* d_in, const int* in_sizes, int n_in,
                              void* d_out, int out_size, void* d_ws, size_t ws_size,
                              hipStream_t stream) {
  const float* x      = (const float*)d_in[0];
  const float* ln_w   = (const float*)d_in[1];
  const float* attn_w = (const float*)d_in[2];
  const float* proj_w = (const float*)d_in[3];
  const float* theta  = (const float*)d_in[4];
  float* out = (float*)d_out;

  char* ws = (char*)d_ws;
  const size_t SZY  = (size_t)4096 * 1024 * 2;        // 8,388,608
  const size_t SZW  = (size_t)3072 * 1024 * 2;        // 6,291,456
  const size_t SZW2 = (size_t)2048 * 1024 * 2;        // 4,194,304
  const size_t SZQ  = (size_t)2 * 16 * 2048 * 64 * 4; // 16,777,216 (fp32)
  const size_t SZK  = (size_t)2 * 16 * 2048 * 64 * 2; //  8,388,608 (bf16)

  unsigned short* y0 = (unsigned short*)(ws);
  unsigned short* y1 = (unsigned short*)(ws + SZY);
  unsigned short* y2 = (unsigned short*)(ws + 2 * SZY);
  unsigned short* W0 = (unsigned short*)(ws + 3 * SZY);
  unsigned short* W1 = (unsigned short*)(ws + 3 * SZY + SZW);
  unsigned short* W2 = (unsigned short*)(ws + 3 * SZY + 2 * SZW);
  float* Qf          = (float*)(ws + 3 * SZY + 2 * SZW + SZW2);
  unsigned short* K0 = (unsigned short*)(ws + 3 * SZY + 2 * SZW + SZW2 + SZQ);
  unsigned short* K1 = (unsigned short*)(ws + 3 * SZY + 2 * SZW + SZW2 + SZQ + SZK);
  float* E           = (float*)(ws + 3 * SZY + 2 * SZW + SZW2 + SZQ + 2 * SZK);
  float* Einv        = E + T_SEQ;
  // aliases into dead regions (y dead after qkv_*, then reused):
  unsigned short* Ob0 = y0;
  unsigned short* Ob1 = y1;
  unsigned short* PW0 = y2;
  unsigned short* PW1 = y2 + (size_t)1024 * 1024;
  // d_out scratch (16.78 MB): VbT low half, K2 high half; both dead before proj writes
  unsigned short* VbT = (unsigned short*)d_out;
  unsigned short* K2  = (unsigned short*)((char*)d_out + SZK);

  size_t needed = 3 * SZY + 2 * SZW + SZW2 + SZQ + 2 * SZK + 2 * T_SEQ * 4;  // 75,513,856
  if (ws_size < needed) return;  // loud failure: output stays zero

  eta_kernel<<<dim3(8), dim3(256), 0, stream>>>(theta, E, Einv);
  ln_kernel<<<dim3(4096), dim3(256), 0, stream>>>(x, ln_w, y0, y1, y2);
  conv_w3<<<dim3(1536), dim3(256), 0, stream>>>(attn_w, W0, W1, W2);
  qkv_qk<<<dim3(16, 32), dim3(256), 0, stream>>>(y0, y1, y2, W0, W1, W2, E, Einv,
                                                 Qf, K0, K1, K2);
  qkv_v<<<dim3(8, 32), dim3(256), 0, stream>>>(y0, y1, W0, W1, VbT);
  attn_kernel<<<dim3(16, 32), dim3(512), 0, stream>>>(Qf, K0, K1, K2, VbT, Ob0, Ob1);
  conv_pw<<<dim3(512), dim3(256), 0, stream>>>(proj_w, PW0, PW1);
  proj_gemm<<<dim3(8, 32), dim3(256), 0, stream>>>(Ob0, Ob1, PW0, PW1, out);
}

// Round 8
// 531.493 us; speedup vs baseline: 2.8361x; 2.8361x over previous
//
#include <hip/hip_runtime.h>
#include <stdint.h>
#include <stddef.h>

typedef __attribute__((ext_vector_type(8))) short short8;
typedef __attribute__((ext_vector_type(4))) float float4v;

#define T_SEQ 2048
#define D_MODEL 1024
#define NH 16
#define HD 64

static __device__ __forceinline__ unsigned short f2bf(float f) {
  unsigned u = __builtin_bit_cast(unsigned, f);
  u += 0x7fffu + ((u >> 16) & 1u);
  return (unsigned short)(u >> 16);
}
static __device__ __forceinline__ float bf2f(unsigned short h) {
  unsigned u = ((unsigned)h) << 16;
  return __builtin_bit_cast(float, u);
}
static __device__ __forceinline__ float4v mfma16(short8 a, short8 b, float4v c) {
  return __builtin_amdgcn_mfma_f32_16x16x32_bf16(a, b, c, 0, 0, 0);
}
// fp32 -> 3 bf16 terms (sum reproduces f to ~2^-27 rel)
static __device__ __forceinline__ void split3(float f, unsigned short& h0,
                                              unsigned short& h1, unsigned short& h2) {
  h0 = f2bf(f);
  float r1 = f - bf2f(h0);
  h1 = f2bf(r1);
  float r2 = r1 - bf2f(h1);
  h2 = f2bf(r2);
}
// fp32 -> 2 bf16 terms (~2^-18 rel)
static __device__ __forceinline__ void split2(float f, unsigned short& h0, unsigned short& h1) {
  h0 = f2bf(f);
  h1 = f2bf(f - bf2f(h0));
}

// async global->LDS, 16 B per lane (global_load_lds_dwordx4); guarded fallback
static __device__ __forceinline__ void stage16(const unsigned short* g, unsigned short* l) {
#if __has_builtin(__builtin_amdgcn_global_load_lds)
  __builtin_amdgcn_global_load_lds(
      (const __attribute__((address_space(1))) unsigned int*)g,
      (__attribute__((address_space(3))) unsigned int*)l, 16, 0, 0);
#else
  *(short8*)l = *(const short8*)g;
#endif
}

// ---------------- eta tables ----------------
__global__ void eta_kernel(const float* theta, float* E, float* Einv) {
  int i = blockIdx.x * blockDim.x + threadIdx.x;
  if (i >= T_SEQ) return;
  float th = theta[0];
  float h = log1pf(expf(th));            // softplus
  float t = 1.0f + h * (float)i;         // T0 = 1
  float eta = 3.0f * logf(t);            // C_LOG = 3
  eta = fminf(fmaxf(eta, -50.0f), 50.0f);
  E[i] = expf(eta);
  Einv[i] = expf(-eta);
}

// ---------------- LayerNorm (fp32 in) -> 3-way split y ----------------
__global__ __launch_bounds__(256) void ln_kernel(const float* x, const float* wgt,
                          unsigned short* y0, unsigned short* y1, unsigned short* y2) {
  int row = blockIdx.x;
  int tid = threadIdx.x;
  const float* xr = x + (size_t)row * D_MODEL;
  float v[4];
  float sum = 0.f, ssq = 0.f;
  for (int it = 0; it < 4; ++it) {
    float f = xr[tid + 256 * it];
    v[it] = f;
    sum += f; ssq += f * f;
  }
  for (int off = 32; off >= 1; off >>= 1) {
    sum += __shfl_xor(sum, off, 64);
    ssq += __shfl_xor(ssq, off, 64);
  }
  __shared__ float rs[4], rq[4];
  int w = tid >> 6;
  if ((tid & 63) == 0) { rs[w] = sum; rq[w] = ssq; }
  __syncthreads();
  sum = rs[0] + rs[1] + rs[2] + rs[3];
  ssq = rq[0] + rq[1] + rq[2] + rq[3];
  float mu = sum * (1.0f / D_MODEL);
  float var = ssq * (1.0f / D_MODEL) - mu * mu;
  float rstd = rsqrtf(var + 1e-5f);
  for (int it = 0; it < 4; ++it) {
    int d = tid + 256 * it;
    float y = (v[it] - mu) * rstd * wgt[d];
    unsigned short h0, h1, h2;
    split3(y, h0, h1, h2);
    size_t o = (size_t)row * D_MODEL + d;
    y0[o] = h0; y1[o] = h1; y2[o] = h2;
  }
}

// ---------------- attn_w (fp32) -> split3; W2 only for rows < 2048 (Q,K) ----------------
__global__ __launch_bounds__(256) void conv_w3(const float* src, unsigned short* W0,
                                               unsigned short* W1, unsigned short* W2) {
  size_t base = ((size_t)blockIdx.x * 256 + threadIdx.x) * 8;
  int row = (int)(base >> 10);
  short8 a, b, c;
  for (int j = 0; j < 8; ++j) {
    unsigned short h0, h1, h2;
    split3(src[base + j], h0, h1, h2);
    a[j] = (short)h0; b[j] = (short)h1; c[j] = (short)h2;
  }
  *(short8*)(W0 + base) = a;
  *(short8*)(W1 + base) = b;
  if (row < 2048) *(short8*)(W2 + base) = c;
}

// ---------------- proj_w (fp32) -> split2 ----------------
__global__ __launch_bounds__(256) void conv_pw(const float* src, unsigned short* P0,
                                               unsigned short* P1) {
  size_t base = ((size_t)blockIdx.x * 256 + threadIdx.x) * 8;
  short8 a, b;
  for (int j = 0; j < 8; ++j) {
    unsigned short h0, h1;
    split2(src[base + j], h0, h1);
    a[j] = (short)h0; b[j] = (short)h1;
  }
  *(short8*)(P0 + base) = a;
  *(short8*)(P1 + base) = b;
}

// ---------------- Q,K GEMM: LDS-staged 128x128 tile, 6-term split ----------------
// Epilogue prescales: Q *= E[t]*0.125*log2(e)  (softmax in base-2 domain),
//                     K *= Einv[t], then split3 to bf16.
__global__ __launch_bounds__(256) void qkv_qk(
    const unsigned short* y0, const unsigned short* y1, const unsigned short* y2,
    const unsigned short* W0, const unsigned short* W1, const unsigned short* W2,
    const float* E, const float* Einv,
    float* Qf, unsigned short* K0, unsigned short* K1, unsigned short* K2) {
  __shared__ unsigned short As[3][128 * 32];   // 8 KB each
  __shared__ unsigned short Bs[3][128 * 32];
  int tid = threadIdx.x;
  int w = tid >> 6, lane = tid & 63, q4 = lane >> 4, ln = lane & 15;
  int wr = w >> 1, wc = w & 1;
  int n0g = blockIdx.x * 128;   // 0..2047 (Q then K region)
  int m0 = blockIdx.y * 128;
  const unsigned short* Asrc[3] = {y0, y1, y2};
  const unsigned short* Bsrc[3] = {W0, W1, W2};

  float4v zero = {0.f, 0.f, 0.f, 0.f};
  float4v acc[4][4];
  for (int mt = 0; mt < 4; ++mt)
    for (int ct = 0; ct < 4; ++ct) acc[mt][ct] = zero;

  int srow = tid >> 2;          // 0..63
  int kpart = tid & 3;          // 0..3
  unsigned lds_off = (unsigned)tid * 16;   // bytes

  for (int k0 = 0; k0 < D_MODEL; k0 += 32) {
    __syncthreads();   // prev round's ds_reads done before overwrite
    for (int i = 0; i < 2; ++i) {
      size_t arow = (size_t)(m0 + srow + i * 64) * D_MODEL + k0 + kpart * 8;
      size_t brow = (size_t)(n0g + srow + i * 64) * D_MODEL + k0 + kpart * 8;
      for (int s = 0; s < 3; ++s) {
        stage16(Asrc[s] + arow, (unsigned short*)((char*)As[s] + lds_off + i * 4096));
        stage16(Bsrc[s] + brow, (unsigned short*)((char*)Bs[s] + lds_off + i * 4096));
      }
    }
    __syncthreads();   // staging visible

    short8 af[4][3];
    for (int mt = 0; mt < 4; ++mt)
      for (int s = 0; s < 3; ++s)
        af[mt][s] = *(const short8*)&As[s][(wr * 64 + mt * 16 + ln) * 32 + q4 * 8];
    for (int ct = 0; ct < 4; ++ct) {
      int brow = (wc * 64 + ct * 16 + ln) * 32 + q4 * 8;
      short8 b0 = *(const short8*)&Bs[0][brow];
      short8 b1 = *(const short8*)&Bs[1][brow];
      short8 b2 = *(const short8*)&Bs[2][brow];
      for (int mt = 0; mt < 4; ++mt) {
        float4v a = acc[mt][ct];
        a = mfma16(af[mt][0], b0, a);
        a = mfma16(af[mt][1], b0, a);
        a = mfma16(af[mt][0], b1, a);
        a = mfma16(af[mt][1], b1, a);
        a = mfma16(af[mt][0], b2, a);
        a = mfma16(af[mt][2], b0, a);
        acc[mt][ct] = a;
      }
    }
  }

  int region = n0g >> 10;            // 0=Q 1=K
  for (int mt = 0; mt < 4; ++mt)
    for (int ct = 0; ct < 4; ++ct)
      for (int r = 0; r < 4; ++r) {
        int gm = m0 + wr * 64 + mt * 16 + q4 * 4 + r;
        int col = n0g + wc * 64 + ct * 16 + ln;
        int bi = gm >> 11, t = gm & 2047;
        int h = (col & 1023) >> 6, d = col & 63;
        size_t o = ((size_t)(bi * NH + h) * T_SEQ + t) * HD + d;
        float val = acc[mt][ct][r];
        if (region == 0) {
          Qf[o] = val * (E[t] * (0.125f * 1.44269504f));
        } else {
          unsigned short h0, h1, h2;
          split3(val * Einv[t], h0, h1, h2);
          K0[o] = h0; K1[o] = h1; K2[o] = h2;
        }
      }
}

// ---------------- V GEMM: LDS-staged, 3-term, bf16-out transposed [b,h,d,t] ----------------
__global__ __launch_bounds__(256) void qkv_v(
    const unsigned short* y0, const unsigned short* y1,
    const unsigned short* W0, const unsigned short* W1, unsigned short* VbT) {
  __shared__ unsigned short As[2][128 * 32];
  __shared__ unsigned short Bs[2][128 * 32];
  int tid = threadIdx.x;
  int w = tid >> 6, lane = tid & 63, q4 = lane >> 4, ln = lane & 15;
  int wr = w >> 1, wc = w & 1;
  int n0g = blockIdx.x * 128;        // 0..1023 within V region
  int m0 = blockIdx.y * 128;
  const unsigned short* Asrc[2] = {y0, y1};
  const unsigned short* Bsrc[2] = {W0, W1};

  float4v zero = {0.f, 0.f, 0.f, 0.f};
  float4v acc[4][4];
  for (int mt = 0; mt < 4; ++mt)
    for (int ct = 0; ct < 4; ++ct) acc[mt][ct] = zero;

  int srow = tid >> 2, kpart = tid & 3;
  unsigned lds_off = (unsigned)tid * 16;

  for (int k0 = 0; k0 < D_MODEL; k0 += 32) {
    __syncthreads();
    for (int i = 0; i < 2; ++i) {
      size_t arow = (size_t)(m0 + srow + i * 64) * D_MODEL + k0 + kpart * 8;
      size_t brow = (size_t)(2048 + n0g + srow + i * 64) * D_MODEL + k0 + kpart * 8;
      for (int s = 0; s < 2; ++s) {
        stage16(Asrc[s] + arow, (unsigned short*)((char*)As[s] + lds_off + i * 4096));
        stage16(Bsrc[s] + brow, (unsigned short*)((char*)Bs[s] + lds_off + i * 4096));
      }
    }
    __syncthreads();

    short8 af[4][2];
    for (int mt = 0; mt < 4; ++mt)
      for (int s = 0; s < 2; ++s)
        af[mt][s] = *(const short8*)&As[s][(wr * 64 + mt * 16 + ln) * 32 + q4 * 8];
    for (int ct = 0; ct < 4; ++ct) {
      int brow = (wc * 64 + ct * 16 + ln) * 32 + q4 * 8;
      short8 b0 = *(const short8*)&Bs[0][brow];
      short8 b1 = *(const short8*)&Bs[1][brow];
      for (int mt = 0; mt < 4; ++mt) {
        float4v a = acc[mt][ct];
        a = mfma16(af[mt][0], b0, a);
        a = mfma16(af[mt][1], b0, a);
        a = mfma16(af[mt][0], b1, a);
        acc[mt][ct] = a;
      }
    }
  }

  for (int mt = 0; mt < 4; ++mt)
    for (int ct = 0; ct < 4; ++ct) {
      int tb = m0 + wr * 64 + mt * 16 + q4 * 4;   // 4 consecutive t
      int bi = tb >> 11, t = tb & 2047;
      int col = n0g + wc * 64 + ct * 16 + ln;
      int h = col >> 6, d = col & 63;
      unsigned short tmp[4];
      for (int r = 0; r < 4; ++r) tmp[r] = f2bf(acc[mt][ct][r]);
      *(uint64_t*)(VbT + ((size_t)((bi * NH + h) * HD + d) * T_SEQ + t)) =
          *(const uint64_t*)tmp;
    }
}

// ---------------- fused causal attention ----------------
// 4 waves/block (256 thr, default reg budget — r7's launch_bounds(512,4) caused
// catastrophic spills). K/V tiles staged cooperatively into LDS via
// global_load_lds, double-buffered, 1 barrier per jt: prefetch of tile jt+1
// overlaps compute of tile jt. XOR chunk swizzle kills ds_read bank conflicts.
__global__ __launch_bounds__(256) void attn_kernel(
    const float* Qf, const unsigned short* K0, const unsigned short* K1,
    const unsigned short* K2, const unsigned short* VbT,
    unsigned short* Ob0, unsigned short* Ob1) {
  __shared__ unsigned short Ks[2][3][4096];   // 2 buf x 3 splits x 64x64 bf16
  __shared__ unsigned short Vs[2][4096];      // 2 buf x 64d x 64t bf16
  __shared__ unsigned short Plds[4][16][72];  // per-wave P tile, padded
  int tid = threadIdx.x;
  int w = tid >> 6, lane = tid & 63, q4 = lane >> 4, ln = lane & 15;
  int px = blockIdx.x;   // 0..15 -> q-tile pair (px, 31-px): 33 jt-iters/block
  int bh = blockIdx.y;
  const float* Qb = Qf + (size_t)bh * T_SEQ * HD;
  const unsigned short* Kb0 = K0 + (size_t)bh * T_SEQ * HD;
  const unsigned short* Kb1 = K1 + (size_t)bh * T_SEQ * HD;
  const unsigned short* Kb2 = K2 + (size_t)bh * T_SEQ * HD;
  const unsigned short* Vb = VbT + (size_t)bh * HD * T_SEQ;
  int b = bh >> 4, hh = bh & 15;
  float4v zero = {0.f, 0.f, 0.f, 0.f};
  short8 ones;
  for (int j = 0; j < 8; ++j) ones[j] = (short)(unsigned short)0x3F80;  // bf16 1.0

  // staging decomposition: slot tid -> (row=tid>>3, chunk_slot=tid&7);
  // source chunk = chunk_slot ^ (row&7)  (XOR swizzle, wave-uniform LDS base)
  int srow = tid >> 3, scs = tid & 7;
  int scd = scs ^ (srow & 7);
  int swz = ln & 7;   // read-side swizzle key

  for (int half = 0; half < 2; ++half) {
    int qt = half ? (31 - px) : px;
    int q0 = qt * 64;
    int ibase = q0 + w * 16;

    // Q fragments (pre-scaled by E_i*0.125*log2e), 3-way split once per tile
    short8 qa[2][3];
    {
      const float* qp = Qb + (size_t)(ibase + ln) * HD;
      for (int ks = 0; ks < 2; ++ks) {
        float f[8];
        *(float4v*)&f[0] = *(const float4v*)(qp + ks * 32 + q4 * 8);
        *(float4v*)&f[4] = *(const float4v*)(qp + ks * 32 + q4 * 8 + 4);
        for (int j = 0; j < 8; ++j) {
          unsigned short h0, h1, h2;
          split3(f[j], h0, h1, h2);
          qa[ks][0][j] = (short)h0; qa[ks][1][j] = (short)h1; qa[ks][2][j] = (short)h2;
        }
      }
    }

    float m_r[4] = {-3e38f, -3e38f, -3e38f, -3e38f};
    float4v lacc = zero;
    float4v oacc[4];
    for (int c = 0; c < 4; ++c) oacc[c] = zero;

    __syncthreads();   // all waves done reading Ks/Vs from previous half
    // stage jt=0 into buffer 0
    for (int i = 0; i < 2; ++i) {
      size_t go = (size_t)(srow + i * 32) * 64 + scd * 8;   // j0 = 0
      int lo = tid * 8 + i * 2048;
      stage16(Kb0 + go, &Ks[0][0][lo]);
      stage16(Kb1 + go, &Ks[0][1][lo]);
      stage16(Kb2 + go, &Ks[0][2][lo]);
      stage16(Vb + (size_t)(srow + i * 32) * T_SEQ + scd * 8, &Vs[0][lo]);
    }

    for (int jt = 0; jt <= qt; ++jt) {
      int cur = jt & 1;
      int j0 = jt * 64;
      __syncthreads();   // buf[cur] staged; prev reads of buf[cur^1] drained
      if (jt < qt) {     // prefetch next tile into the other buffer
        int jn = j0 + 64;
        for (int i = 0; i < 2; ++i) {
          size_t go = (size_t)(jn + srow + i * 32) * 64 + scd * 8;
          int lo = tid * 8 + i * 2048;
          stage16(Kb0 + go, &Ks[cur ^ 1][0][lo]);
          stage16(Kb1 + go, &Ks[cur ^ 1][1][lo]);
          stage16(Kb2 + go, &Ks[cur ^ 1][2][lo]);
          stage16(Vb + (size_t)(srow + i * 32) * T_SEQ + jn + scd * 8,
                  &Vs[cur ^ 1][lo]);
        }
      }
      bool diag = (jt == qt);
      float p[4][4];   // [c][r]: base-2 logits, then probabilities
      for (int c = 0; c < 4; ++c) {
        int jl = c * 16 + ln;
        float4v s = zero;
        for (int ks = 0; ks < 2; ++ks) {
          int koff = (jl * 8 + ((ks * 4 + q4) ^ swz)) * 8;
          short8 k0v = *(const short8*)&Ks[cur][0][koff];
          short8 k1v = *(const short8*)&Ks[cur][1][koff];
          short8 k2v = *(const short8*)&Ks[cur][2][koff];
          s = mfma16(qa[ks][0], k0v, s);
          s = mfma16(qa[ks][1], k0v, s);
          s = mfma16(qa[ks][0], k1v, s);
          s = mfma16(qa[ks][1], k1v, s);
          s = mfma16(qa[ks][0], k2v, s);
          s = mfma16(qa[ks][2], k0v, s);
        }
        int jrow = j0 + jl;
        for (int r = 0; r < 4; ++r) {
          float l = s[r];
          if (diag && jrow > ibase + q4 * 4 + r) l = -3e38f;   // causal mask
          p[c][r] = l;
        }
      }
      float alpha[4], mnew[4];
      for (int r = 0; r < 4; ++r) {
        float tm = fmaxf(fmaxf(p[0][r], p[1][r]), fmaxf(p[2][r], p[3][r]));
        for (int off = 8; off >= 1; off >>= 1) tm = fmaxf(tm, __shfl_xor(tm, off, 16));
        mnew[r] = fmaxf(m_r[r], tm);
        alpha[r] = exp2f(m_r[r] - mnew[r]);
        m_r[r] = mnew[r];
      }
      for (int c = 0; c < 4; ++c)
        for (int r = 0; r < 4; ++r)
          p[c][r] = exp2f(p[c][r] - mnew[r]);
      for (int c = 0; c < 4; ++c)
        for (int r = 0; r < 4; ++r) oacc[c][r] *= alpha[r];
      for (int r = 0; r < 4; ++r) lacc[r] *= alpha[r];

      // within-wave LDS transpose (C-layout -> A-layout), wave-private slice
      __asm__ __volatile__("" ::: "memory");
      for (int c = 0; c < 4; ++c)
        for (int r = 0; r < 4; ++r)
          Plds[w][q4 * 4 + r][c * 16 + ln] = f2bf(p[c][r]);
      __asm__ __volatile__("" ::: "memory");

      // P·V from LDS + row-sum l via ones-column MFMA
      for (int ks = 0; ks < 2; ++ks) {
        short8 pa = *(const short8*)&Plds[w][ln][ks * 32 + q4 * 8];
        for (int c = 0; c < 4; ++c) {
          int voff = ((c * 16 + ln) * 8 + ((ks * 4 + q4) ^ swz)) * 8;
          short8 vb = *(const short8*)&Vs[cur][voff];
          oacc[c] = mfma16(pa, vb, oacc[c]);
        }
        lacc = mfma16(pa, ones, lacc);
      }
      __asm__ __volatile__("" ::: "memory");
    }

    for (int c = 0; c < 4; ++c)
      for (int r = 0; r < 4; ++r) {
        int i = ibase + q4 * 4 + r;
        float val = oacc[c][r] / lacc[r];
        unsigned short h0, h1;
        split2(val, h0, h1);
        size_t o = ((size_t)(b * T_SEQ + i)) * D_MODEL + hh * 64 + c * 16 + ln;
        Ob0[o] = h0; Ob1[o] = h1;
      }
  }
}

// ---------------- output projection: LDS-staged, 3-term, fp32 out ----------------
__global__ __launch_bounds__(256) void proj_gemm(
    const unsigned short* A0, const unsigned short* A1,
    const unsigned short* P0, const unsigned short* P1, float* out) {
  __shared__ unsigned short As[2][128 * 32];
  __shared__ unsigned short Bs[2][128 * 32];
  int tid = threadIdx.x;
  int w = tid >> 6, lane = tid & 63, q4 = lane >> 4, ln = lane & 15;
  int wr = w >> 1, wc = w & 1;
  int n0g = blockIdx.x * 128;
  int m0 = blockIdx.y * 128;
  const unsigned short* Asrc[2] = {A0, A1};
  const unsigned short* Bsrc[2] = {P0, P1};

  float4v zero = {0.f, 0.f, 0.f, 0.f};
  float4v acc[4][4];
  for (int mt = 0; mt < 4; ++mt)
    for (int ct = 0; ct < 4; ++ct) acc[mt][ct] = zero;

  int srow = tid >> 2, kpart = tid & 3;
  unsigned lds_off = (unsigned)tid * 16;

  for (int k0 = 0; k0 < D_MODEL; k0 += 32) {
    __syncthreads();
    for (int i = 0; i < 2; ++i) {
      size_t arow = (size_t)(m0 + srow + i * 64) * D_MODEL + k0 + kpart * 8;
      size_t brow = (size_t)(n0g + srow + i * 64) * D_MODEL + k0 + kpart * 8;
      for (int s = 0; s < 2; ++s) {
        stage16(Asrc[s] + arow, (unsigned short*)((char*)As[s] + lds_off + i * 4096));
        stage16(Bsrc[s] + brow, (unsigned short*)((char*)Bs[s] + lds_off + i * 4096));
      }
    }
    __syncthreads();

    short8 af[4][2];
    for (int mt = 0; mt < 4; ++mt)
      for (int s = 0; s < 2; ++s)
        af[mt][s] = *(const short8*)&As[s][(wr * 64 + mt * 16 + ln) * 32 + q4 * 8];
    for (int ct = 0; ct < 4; ++ct) {
      int brow = (wc * 64 + ct * 16 + ln) * 32 + q4 * 8;
      short8 b0 = *(const short8*)&Bs[0][brow];
      short8 b1 = *(const short8*)&Bs[1][brow];
      for (int mt = 0; mt < 4; ++mt) {
        float4v a = acc[mt][ct];
        a = mfma16(af[mt][0], b0, a);
        a = mfma16(af[mt][1], b0, a);
        a = mfma16(af[mt][0], b1, a);
        acc[mt][ct] = a;
      }
    }
  }

  for (int mt = 0; mt < 4; ++mt)
    for (int ct = 0; ct < 4; ++ct)
      for (int r = 0; r < 4; ++r) {
        int gm = m0 + wr * 64 + mt * 16 + q4 * 4 + r;
        int col = n0g + wc * 64 + ct * 16 + ln;
        out[(size_t)gm * D_MODEL + col] = acc[mt][ct][r];
      }
}

extern "C" void kernel_launch(void* const* d_in, const int* in_sizes, int n_in,
                              void* d_out, int out_size, void* d_ws, size_t ws_size,
                              hipStream_t stream) {
  const float* x      = (const float*)d_in[0];
  const float* ln_w   = (const float*)d_in[1];
  const float* attn_w = (const float*)d_in[2];
  const float* proj_w = (const float*)d_in[3];
  const float* theta  = (const float*)d_in[4];
  float* out = (float*)d_out;

  char* ws = (char*)d_ws;
  const size_t SZY  = (size_t)4096 * 1024 * 2;        // 8,388,608
  const size_t SZW  = (size_t)3072 * 1024 * 2;        // 6,291,456
  const size_t SZW2 = (size_t)2048 * 1024 * 2;        // 4,194,304
  const size_t SZQ  = (size_t)2 * 16 * 2048 * 64 * 4; // 16,777,216 (fp32)
  const size_t SZK  = (size_t)2 * 16 * 2048 * 64 * 2; //  8,388,608 (bf16)

  unsigned short* y0 = (unsigned short*)(ws);
  unsigned short* y1 = (unsigned short*)(ws + SZY);
  unsigned short* y2 = (unsigned short*)(ws + 2 * SZY);
  unsigned short* W0 = (unsigned short*)(ws + 3 * SZY);
  unsigned short* W1 = (unsigned short*)(ws + 3 * SZY + SZW);
  unsigned short* W2 = (unsigned short*)(ws + 3 * SZY + 2 * SZW);
  float* Qf          = (float*)(ws + 3 * SZY + 2 * SZW + SZW2);
  unsigned short* K0 = (unsigned short*)(ws + 3 * SZY + 2 * SZW + SZW2 + SZQ);
  unsigned short* K1 = (unsigned short*)(ws + 3 * SZY + 2 * SZW + SZW2 + SZQ + SZK);
  float* E           = (float*)(ws + 3 * SZY + 2 * SZW + SZW2 + SZQ + 2 * SZK);
  float* Einv        = E + T_SEQ;
  // aliases into dead regions (y dead after qkv_*, then reused):
  unsigned short* Ob0 = y0;
  unsigned short* Ob1 = y1;
  unsigned short* PW0 = y2;
  unsigned short* PW1 = y2 + (size_t)1024 * 1024;
  // d_out scratch (16.78 MB): VbT low half, K2 high half; both dead before proj writes
  unsigned short* VbT = (unsigned short*)d_out;
  unsigned short* K2  = (unsigned short*)((char*)d_out + SZK);

  size_t needed = 3 * SZY + 2 * SZW + SZW2 + SZQ + 2 * SZK + 2 * T_SEQ * 4;  // 75,513,856
  if (ws_size < needed) return;  // loud failure: output stays zero

  eta_kernel<<<dim3(8), dim3(256), 0, stream>>>(theta, E, Einv);
  ln_kernel<<<dim3(4096), dim3(256), 0, stream>>>(x, ln_w, y0, y1, y2);
  conv_w3<<<dim3(1536), dim3(256), 0, stream>>>(attn_w, W0, W1, W2);
  qkv_qk<<<dim3(16, 32), dim3(256), 0, stream>>>(y0, y1, y2, W0, W1, W2, E, Einv,
                                                 Qf, K0, K1, K2);
  qkv_v<<<dim3(8, 32), dim3(256), 0, stream>>>(y0, y1, W0, W1, VbT);
  attn_kernel<<<dim3(16, 32), dim3(256), 0, stream>>>(Qf, K0, K1, K2, VbT, Ob0, Ob1);
  conv_pw<<<dim3(512), dim3(256), 0, stream>>>(proj_w, PW0, PW1);
  proj_gemm<<<dim3(8, 32), dim3(256), 0, stream>>>(Ob0, Ob1, PW0, PW1, out);
}

// Round 9
// 381.838 us; speedup vs baseline: 3.9477x; 1.3919x over previous
//
#include <hip/hip_runtime.h>
#include <stdint.h>
#include <stddef.h>

typedef __attribute__((ext_vector_type(8))) short short8;
typedef __attribute__((ext_vector_type(4))) float float4v;

#define T_SEQ 2048
#define D_MODEL 1024
#define NH 16
#define HD 64

static __device__ __forceinline__ unsigned short f2bf(float f) {
  unsigned u = __builtin_bit_cast(unsigned, f);
  u += 0x7fffu + ((u >> 16) & 1u);
  return (unsigned short)(u >> 16);
}
static __device__ __forceinline__ float bf2f(unsigned short h) {
  unsigned u = ((unsigned)h) << 16;
  return __builtin_bit_cast(float, u);
}
static __device__ __forceinline__ float4v mfma16(short8 a, short8 b, float4v c) {
  return __builtin_amdgcn_mfma_f32_16x16x32_bf16(a, b, c, 0, 0, 0);
}
// fp32 -> 3 bf16 terms (sum reproduces f to ~2^-27 rel)
static __device__ __forceinline__ void split3(float f, unsigned short& h0,
                                              unsigned short& h1, unsigned short& h2) {
  h0 = f2bf(f);
  float r1 = f - bf2f(h0);
  h1 = f2bf(r1);
  float r2 = r1 - bf2f(h1);
  h2 = f2bf(r2);
}
// fp32 -> 2 bf16 terms (~2^-18 rel)
static __device__ __forceinline__ void split2(float f, unsigned short& h0, unsigned short& h1) {
  h0 = f2bf(f);
  h1 = f2bf(f - bf2f(h0));
}

// async global->LDS, 16 B per lane (global_load_lds_dwordx4); guarded fallback
static __device__ __forceinline__ void stage16(const unsigned short* g, unsigned short* l) {
#if __has_builtin(__builtin_amdgcn_global_load_lds)
  __builtin_amdgcn_global_load_lds(
      (const __attribute__((address_space(1))) unsigned int*)g,
      (__attribute__((address_space(3))) unsigned int*)l, 16, 0, 0);
#else
  *(short8*)l = *(const short8*)g;
#endif
}

// ---------------- eta tables ----------------
__global__ void eta_kernel(const float* theta, float* E, float* Einv) {
  int i = blockIdx.x * blockDim.x + threadIdx.x;
  if (i >= T_SEQ) return;
  float th = theta[0];
  float h = log1pf(expf(th));            // softplus
  float t = 1.0f + h * (float)i;         // T0 = 1
  float eta = 3.0f * logf(t);            // C_LOG = 3
  eta = fminf(fmaxf(eta, -50.0f), 50.0f);
  E[i] = expf(eta);
  Einv[i] = expf(-eta);
}

// ---------------- LayerNorm (fp32 in) -> 3-way split y ----------------
__global__ __launch_bounds__(256) void ln_kernel(const float* x, const float* wgt,
                          unsigned short* y0, unsigned short* y1, unsigned short* y2) {
  int row = blockIdx.x;
  int tid = threadIdx.x;
  const float* xr = x + (size_t)row * D_MODEL;
  float v[4];
  float sum = 0.f, ssq = 0.f;
  for (int it = 0; it < 4; ++it) {
    float f = xr[tid + 256 * it];
    v[it] = f;
    sum += f; ssq += f * f;
  }
  for (int off = 32; off >= 1; off >>= 1) {
    sum += __shfl_xor(sum, off, 64);
    ssq += __shfl_xor(ssq, off, 64);
  }
  __shared__ float rs[4], rq[4];
  int w = tid >> 6;
  if ((tid & 63) == 0) { rs[w] = sum; rq[w] = ssq; }
  __syncthreads();
  sum = rs[0] + rs[1] + rs[2] + rs[3];
  ssq = rq[0] + rq[1] + rq[2] + rq[3];
  float mu = sum * (1.0f / D_MODEL);
  float var = ssq * (1.0f / D_MODEL) - mu * mu;
  float rstd = rsqrtf(var + 1e-5f);
  for (int it = 0; it < 4; ++it) {
    int d = tid + 256 * it;
    float y = (v[it] - mu) * rstd * wgt[d];
    unsigned short h0, h1, h2;
    split3(y, h0, h1, h2);
    size_t o = (size_t)row * D_MODEL + d;
    y0[o] = h0; y1[o] = h1; y2[o] = h2;
  }
}

// ---------------- attn_w (fp32) -> split3; W2 only for rows < 2048 (Q,K) ----------------
__global__ __launch_bounds__(256) void conv_w3(const float* src, unsigned short* W0,
                                               unsigned short* W1, unsigned short* W2) {
  size_t base = ((size_t)blockIdx.x * 256 + threadIdx.x) * 8;
  int row = (int)(base >> 10);
  short8 a, b, c;
  for (int j = 0; j < 8; ++j) {
    unsigned short h0, h1, h2;
    split3(src[base + j], h0, h1, h2);
    a[j] = (short)h0; b[j] = (short)h1; c[j] = (short)h2;
  }
  *(short8*)(W0 + base) = a;
  *(short8*)(W1 + base) = b;
  if (row < 2048) *(short8*)(W2 + base) = c;
}

// ---------------- proj_w (fp32) -> split2 ----------------
__global__ __launch_bounds__(256) void conv_pw(const float* src, unsigned short* P0,
                                               unsigned short* P1) {
  size_t base = ((size_t)blockIdx.x * 256 + threadIdx.x) * 8;
  short8 a, b;
  for (int j = 0; j < 8; ++j) {
    unsigned short h0, h1;
    split2(src[base + j], h0, h1);
    a[j] = (short)h0; b[j] = (short)h1;
  }
  *(short8*)(P0 + base) = a;
  *(short8*)(P1 + base) = b;
}

// ---------------- Q,K GEMM: LDS-staged 128x128 tile, 6-term split ----------------
// Epilogue: prescale (Q *= E[t]*0.125*log2e; K *= Einv[t] then split3), transpose
// through LDS, and write fully-coalesced block-linear regions (fixes the 1.1 GB
// HBM write amplification measured in r8: scattered 2B/4B stores -> 64B sectors).
__global__ __launch_bounds__(256) void qkv_qk(
    const unsigned short* y0, const unsigned short* y1, const unsigned short* y2,
    const unsigned short* W0, const unsigned short* W1, const unsigned short* W2,
    const float* E, const float* Einv,
    float* Qf, unsigned short* K0, unsigned short* K1, unsigned short* K2) {
  __shared__ unsigned short SB[6 * 4096];   // As = SB[0..2], Bs = SB[3..5]; 48 KB
  int tid = threadIdx.x;
  int w = tid >> 6, lane = tid & 63, q4 = lane >> 4, ln = lane & 15;
  int wr = w >> 1, wc = w & 1;
  int n0g = blockIdx.x * 128;   // 0..2047 (Q then K region)
  int m0 = blockIdx.y * 128;
  const unsigned short* Asrc[3] = {y0, y1, y2};
  const unsigned short* Bsrc[3] = {W0, W1, W2};

  float4v zero = {0.f, 0.f, 0.f, 0.f};
  float4v acc[4][4];
  for (int mt = 0; mt < 4; ++mt)
    for (int ct = 0; ct < 4; ++ct) acc[mt][ct] = zero;

  int srow = tid >> 2;          // 0..63
  int kpart = tid & 3;          // 0..3
  unsigned lds_off = (unsigned)tid * 16;   // bytes

  for (int k0 = 0; k0 < D_MODEL; k0 += 32) {
    __syncthreads();   // prev round's ds_reads done before overwrite
    for (int i = 0; i < 2; ++i) {
      size_t arow = (size_t)(m0 + srow + i * 64) * D_MODEL + k0 + kpart * 8;
      size_t brow = (size_t)(n0g + srow + i * 64) * D_MODEL + k0 + kpart * 8;
      for (int s = 0; s < 3; ++s) {
        stage16(Asrc[s] + arow, (unsigned short*)((char*)(SB + s * 4096) + lds_off + i * 4096));
        stage16(Bsrc[s] + brow, (unsigned short*)((char*)(SB + (3 + s) * 4096) + lds_off + i * 4096));
      }
    }
    __syncthreads();   // staging visible

    short8 af[4][3];
    for (int mt = 0; mt < 4; ++mt)
      for (int s = 0; s < 3; ++s)
        af[mt][s] = *(const short8*)(SB + s * 4096 + (wr * 64 + mt * 16 + ln) * 32 + q4 * 8);
    for (int ct = 0; ct < 4; ++ct) {
      int brow = (wc * 64 + ct * 16 + ln) * 32 + q4 * 8;
      short8 b0 = *(const short8*)(SB + 3 * 4096 + brow);
      short8 b1 = *(const short8*)(SB + 4 * 4096 + brow);
      short8 b2 = *(const short8*)(SB + 5 * 4096 + brow);
      for (int mt = 0; mt < 4; ++mt) {
        float4v a = acc[mt][ct];
        a = mfma16(af[mt][0], b0, a);
        a = mfma16(af[mt][1], b0, a);
        a = mfma16(af[mt][0], b1, a);
        a = mfma16(af[mt][1], b1, a);
        a = mfma16(af[mt][0], b2, a);
        a = mfma16(af[mt][2], b0, a);
        acc[mt][ct] = a;
      }
    }
  }

  // ---- coalesced epilogue through LDS ----
  int region = n0g >> 10;            // 0=Q 1=K
  int bi = m0 >> 11;
  int m0g = m0 & 2047;
  __syncthreads();                   // main-loop LDS reads done before reuse
  if (region == 0) {
    float* Ql = (float*)SB;          // [128][64] fp32 = 32 KB
    for (int h = 0; h < 2; ++h) {
      if (wc == h) {
        for (int mt = 0; mt < 4; ++mt)
          for (int ct = 0; ct < 4; ++ct)
            for (int r = 0; r < 4; ++r) {
              int t_loc = wr * 64 + mt * 16 + q4 * 4 + r;
              int d = ct * 16 + ln;
              int t = m0g + t_loc;
              Ql[t_loc * 64 + d] = acc[mt][ct][r] * (E[t] * 0.1803368801f); // 0.125*log2e
            }
      }
      __syncthreads();
      int h_glob = ((n0g + h * 64) & 1023) >> 6;
      float* dst = Qf + ((size_t)(bi * NH + h_glob) * T_SEQ + m0g) * HD;
      for (int it = 0; it < 8; ++it) {
        int idx = it * 256 + tid;            // 2048 chunks x 16 B = 32 KB
        *(float4v*)(dst + idx * 4) = *(const float4v*)(Ql + idx * 4);
      }
      __syncthreads();
    }
  } else {
    unsigned short* Kl = SB;         // [3][128][64] bf16 = 48 KB
    for (int h = 0; h < 2; ++h) {
      if (wc == h) {
        for (int mt = 0; mt < 4; ++mt)
          for (int ct = 0; ct < 4; ++ct)
            for (int r = 0; r < 4; ++r) {
              int t_loc = wr * 64 + mt * 16 + q4 * 4 + r;
              int d = ct * 16 + ln;
              int t = m0g + t_loc;
              unsigned short h0, h1, h2;
              split3(acc[mt][ct][r] * Einv[t], h0, h1, h2);
              Kl[t_loc * 64 + d] = h0;
              Kl[8192 + t_loc * 64 + d] = h1;
              Kl[16384 + t_loc * 64 + d] = h2;
            }
      }
      __syncthreads();
      int h_glob = ((n0g + h * 64) & 1023) >> 6;
      size_t base = ((size_t)(bi * NH + h_glob) * T_SEQ + m0g) * HD;
      unsigned short* dsts[3] = {K0 + base, K1 + base, K2 + base};
      for (int s = 0; s < 3; ++s)
        for (int it = 0; it < 4; ++it) {
          int idx = it * 256 + tid;          // 1024 chunks x 16 B = 16 KB
          *(short8*)(dsts[s] + idx * 8) = *(const short8*)(Kl + s * 8192 + idx * 8);
        }
      __syncthreads();
    }
  }
}

// ---------------- V GEMM: LDS-staged, 3-term, coalesced transposed write ----------------
__global__ __launch_bounds__(256) void qkv_v(
    const unsigned short* y0, const unsigned short* y1,
    const unsigned short* W0, const unsigned short* W1, unsigned short* VbT) {
  __shared__ unsigned short SB[4 * 4096];   // As = SB[0..1], Bs = SB[2..3]; 32 KB
  int tid = threadIdx.x;
  int w = tid >> 6, lane = tid & 63, q4 = lane >> 4, ln = lane & 15;
  int wr = w >> 1, wc = w & 1;
  int n0g = blockIdx.x * 128;        // 0..1023 within V region
  int m0 = blockIdx.y * 128;
  const unsigned short* Asrc[2] = {y0, y1};
  const unsigned short* Bsrc[2] = {W0, W1};

  float4v zero = {0.f, 0.f, 0.f, 0.f};
  float4v acc[4][4];
  for (int mt = 0; mt < 4; ++mt)
    for (int ct = 0; ct < 4; ++ct) acc[mt][ct] = zero;

  int srow = tid >> 2, kpart = tid & 3;
  unsigned lds_off = (unsigned)tid * 16;

  for (int k0 = 0; k0 < D_MODEL; k0 += 32) {
    __syncthreads();
    for (int i = 0; i < 2; ++i) {
      size_t arow = (size_t)(m0 + srow + i * 64) * D_MODEL + k0 + kpart * 8;
      size_t brow = (size_t)(2048 + n0g + srow + i * 64) * D_MODEL + k0 + kpart * 8;
      for (int s = 0; s < 2; ++s) {
        stage16(Asrc[s] + arow, (unsigned short*)((char*)(SB + s * 4096) + lds_off + i * 4096));
        stage16(Bsrc[s] + brow, (unsigned short*)((char*)(SB + (2 + s) * 4096) + lds_off + i * 4096));
      }
    }
    __syncthreads();

    short8 af[4][2];
    for (int mt = 0; mt < 4; ++mt)
      for (int s = 0; s < 2; ++s)
        af[mt][s] = *(const short8*)(SB + s * 4096 + (wr * 64 + mt * 16 + ln) * 32 + q4 * 8);
    for (int ct = 0; ct < 4; ++ct) {
      int brow = (wc * 64 + ct * 16 + ln) * 32 + q4 * 8;
      short8 b0 = *(const short8*)(SB + 2 * 4096 + brow);
      short8 b1 = *(const short8*)(SB + 3 * 4096 + brow);
      for (int mt = 0; mt < 4; ++mt) {
        float4v a = acc[mt][ct];
        a = mfma16(af[mt][0], b0, a);
        a = mfma16(af[mt][1], b0, a);
        a = mfma16(af[mt][0], b1, a);
        acc[mt][ct] = a;
      }
    }
  }

  // ---- coalesced transposed epilogue: VbT[(bi*NH+h)*HD + d][t] ----
  int bi = m0 >> 11;
  int m0g = m0 & 2047;
  __syncthreads();
  unsigned short* Vl = SB;           // [64][128] bf16 = 16 KB
  for (int h = 0; h < 2; ++h) {
    if (wc == h) {
      for (int mt = 0; mt < 4; ++mt)
        for (int ct = 0; ct < 4; ++ct)
          for (int r = 0; r < 4; ++r) {
            int t_loc = wr * 64 + mt * 16 + q4 * 4 + r;
            int d = ct * 16 + ln;
            Vl[d * 128 + t_loc] = f2bf(acc[mt][ct][r]);
          }
    }
    __syncthreads();
    int h_glob = (n0g + h * 64) >> 6;
    size_t base = (size_t)(bi * NH + h_glob) * HD * T_SEQ + m0g;
    for (int it = 0; it < 4; ++it) {
      int idx = it * 256 + tid;            // 1024 chunks: d = idx>>4, c = idx&15
      int d = idx >> 4, c = idx & 15;
      *(short8*)(VbT + base + (size_t)d * T_SEQ + c * 8) =
          *(const short8*)(Vl + d * 128 + c * 8);
    }
    __syncthreads();
  }
}

// ---------------- fused causal attention ----------------
// 4 waves/block; K/V staged cooperatively into LDS (global_load_lds),
// double-buffered, 1 barrier per jt; XOR chunk swizzle on staging/read.
__global__ __launch_bounds__(256) void attn_kernel(
    const float* Qf, const unsigned short* K0, const unsigned short* K1,
    const unsigned short* K2, const unsigned short* VbT,
    unsigned short* Ob0, unsigned short* Ob1) {
  __shared__ unsigned short Ks[2][3][4096];   // 2 buf x 3 splits x 64x64 bf16
  __shared__ unsigned short Vs[2][4096];      // 2 buf x 64d x 64t bf16
  __shared__ unsigned short Plds[4][16][72];  // per-wave P tile, padded
  int tid = threadIdx.x;
  int w = tid >> 6, lane = tid & 63, q4 = lane >> 4, ln = lane & 15;
  int px = blockIdx.x;   // 0..15 -> q-tile pair (px, 31-px): 33 jt-iters/block
  int bh = blockIdx.y;
  const float* Qb = Qf + (size_t)bh * T_SEQ * HD;
  const unsigned short* Kb0 = K0 + (size_t)bh * T_SEQ * HD;
  const unsigned short* Kb1 = K1 + (size_t)bh * T_SEQ * HD;
  const unsigned short* Kb2 = K2 + (size_t)bh * T_SEQ * HD;
  const unsigned short* Vb = VbT + (size_t)bh * HD * T_SEQ;
  int b = bh >> 4, hh = bh & 15;
  float4v zero = {0.f, 0.f, 0.f, 0.f};
  short8 ones;
  for (int j = 0; j < 8; ++j) ones[j] = (short)(unsigned short)0x3F80;  // bf16 1.0

  int srow = tid >> 3, scs = tid & 7;
  int scd = scs ^ (srow & 7);
  int swz = ln & 7;   // read-side swizzle key

  for (int half = 0; half < 2; ++half) {
    int qt = half ? (31 - px) : px;
    int q0 = qt * 64;
    int ibase = q0 + w * 16;

    short8 qa[2][3];
    {
      const float* qp = Qb + (size_t)(ibase + ln) * HD;
      for (int ks = 0; ks < 2; ++ks) {
        float f[8];
        *(float4v*)&f[0] = *(const float4v*)(qp + ks * 32 + q4 * 8);
        *(float4v*)&f[4] = *(const float4v*)(qp + ks * 32 + q4 * 8 + 4);
        for (int j = 0; j < 8; ++j) {
          unsigned short h0, h1, h2;
          split3(f[j], h0, h1, h2);
          qa[ks][0][j] = (short)h0; qa[ks][1][j] = (short)h1; qa[ks][2][j] = (short)h2;
        }
      }
    }

    float m_r[4] = {-3e38f, -3e38f, -3e38f, -3e38f};
    float4v lacc = zero;
    float4v oacc[4];
    for (int c = 0; c < 4; ++c) oacc[c] = zero;

    __syncthreads();
    for (int i = 0; i < 2; ++i) {
      size_t go = (size_t)(srow + i * 32) * 64 + scd * 8;
      int lo = tid * 8 + i * 2048;
      stage16(Kb0 + go, &Ks[0][0][lo]);
      stage16(Kb1 + go, &Ks[0][1][lo]);
      stage16(Kb2 + go, &Ks[0][2][lo]);
      stage16(Vb + (size_t)(srow + i * 32) * T_SEQ + scd * 8, &Vs[0][lo]);
    }

    for (int jt = 0; jt <= qt; ++jt) {
      int cur = jt & 1;
      int j0 = jt * 64;
      __syncthreads();
      if (jt < qt) {
        int jn = j0 + 64;
        for (int i = 0; i < 2; ++i) {
          size_t go = (size_t)(jn + srow + i * 32) * 64 + scd * 8;
          int lo = tid * 8 + i * 2048;
          stage16(Kb0 + go, &Ks[cur ^ 1][0][lo]);
          stage16(Kb1 + go, &Ks[cur ^ 1][1][lo]);
          stage16(Kb2 + go, &Ks[cur ^ 1][2][lo]);
          stage16(Vb + (size_t)(srow + i * 32) * T_SEQ + jn + scd * 8,
                  &Vs[cur ^ 1][lo]);
        }
      }
      bool diag = (jt == qt);
      float p[4][4];
      for (int c = 0; c < 4; ++c) {
        int jl = c * 16 + ln;
        float4v s = zero;
        for (int ks = 0; ks < 2; ++ks) {
          int koff = (jl * 8 + ((ks * 4 + q4) ^ swz)) * 8;
          short8 k0v = *(const short8*)&Ks[cur][0][koff];
          short8 k1v = *(const short8*)&Ks[cur][1][koff];
          short8 k2v = *(const short8*)&Ks[cur][2][koff];
          s = mfma16(qa[ks][0], k0v, s);
          s = mfma16(qa[ks][1], k0v, s);
          s = mfma16(qa[ks][0], k1v, s);
          s = mfma16(qa[ks][1], k1v, s);
          s = mfma16(qa[ks][0], k2v, s);
          s = mfma16(qa[ks][2], k0v, s);
        }
        int jrow = j0 + jl;
        for (int r = 0; r < 4; ++r) {
          float l = s[r];
          if (diag && jrow > ibase + q4 * 4 + r) l = -3e38f;
          p[c][r] = l;
        }
      }
      float alpha[4], mnew[4];
      for (int r = 0; r < 4; ++r) {
        float tm = fmaxf(fmaxf(p[0][r], p[1][r]), fmaxf(p[2][r], p[3][r]));
        for (int off = 8; off >= 1; off >>= 1) tm = fmaxf(tm, __shfl_xor(tm, off, 16));
        mnew[r] = fmaxf(m_r[r], tm);
        alpha[r] = exp2f(m_r[r] - mnew[r]);
        m_r[r] = mnew[r];
      }
      for (int c = 0; c < 4; ++c)
        for (int r = 0; r < 4; ++r)
          p[c][r] = exp2f(p[c][r] - mnew[r]);
      for (int c = 0; c < 4; ++c)
        for (int r = 0; r < 4; ++r) oacc[c][r] *= alpha[r];
      for (int r = 0; r < 4; ++r) lacc[r] *= alpha[r];

      __asm__ __volatile__("" ::: "memory");
      for (int c = 0; c < 4; ++c)
        for (int r = 0; r < 4; ++r)
          Plds[w][q4 * 4 + r][c * 16 + ln] = f2bf(p[c][r]);
      __asm__ __volatile__("" ::: "memory");

      for (int ks = 0; ks < 2; ++ks) {
        short8 pa = *(const short8*)&Plds[w][ln][ks * 32 + q4 * 8];
        for (int c = 0; c < 4; ++c) {
          int voff = ((c * 16 + ln) * 8 + ((ks * 4 + q4) ^ swz)) * 8;
          short8 vb = *(const short8*)&Vs[cur][voff];
          oacc[c] = mfma16(pa, vb, oacc[c]);
        }
        lacc = mfma16(pa, ones, lacc);
      }
      __asm__ __volatile__("" ::: "memory");
    }

    for (int c = 0; c < 4; ++c)
      for (int r = 0; r < 4; ++r) {
        int i = ibase + q4 * 4 + r;
        float val = oacc[c][r] / lacc[r];
        unsigned short h0, h1;
        split2(val, h0, h1);
        size_t o = ((size_t)(b * T_SEQ + i)) * D_MODEL + hh * 64 + c * 16 + ln;
        Ob0[o] = h0; Ob1[o] = h1;
      }
  }
}

// ---------------- output projection: LDS-staged, 3-term, fp32 out ----------------
__global__ __launch_bounds__(256) void proj_gemm(
    const unsigned short* A0, const unsigned short* A1,
    const unsigned short* P0, const unsigned short* P1, float* out) {
  __shared__ unsigned short SB[4 * 4096];
  int tid = threadIdx.x;
  int w = tid >> 6, lane = tid & 63, q4 = lane >> 4, ln = lane & 15;
  int wr = w >> 1, wc = w & 1;
  int n0g = blockIdx.x * 128;
  int m0 = blockIdx.y * 128;
  const unsigned short* Asrc[2] = {A0, A1};
  const unsigned short* Bsrc[2] = {P0, P1};

  float4v zero = {0.f, 0.f, 0.f, 0.f};
  float4v acc[4][4];
  for (int mt = 0; mt < 4; ++mt)
    for (int ct = 0; ct < 4; ++ct) acc[mt][ct] = zero;

  int srow = tid >> 2, kpart = tid & 3;
  unsigned lds_off = (unsigned)tid * 16;

  for (int k0 = 0; k0 < D_MODEL; k0 += 32) {
    __syncthreads();
    for (int i = 0; i < 2; ++i) {
      size_t arow = (size_t)(m0 + srow + i * 64) * D_MODEL + k0 + kpart * 8;
      size_t brow = (size_t)(n0g + srow + i * 64) * D_MODEL + k0 + kpart * 8;
      for (int s = 0; s < 2; ++s) {
        stage16(Asrc[s] + arow, (unsigned short*)((char*)(SB + s * 4096) + lds_off + i * 4096));
        stage16(Bsrc[s] + brow, (unsigned short*)((char*)(SB + (2 + s) * 4096) + lds_off + i * 4096));
      }
    }
    __syncthreads();

    short8 af[4][2];
    for (int mt = 0; mt < 4; ++mt)
      for (int s = 0; s < 2; ++s)
        af[mt][s] = *(const short8*)(SB + s * 4096 + (wr * 64 + mt * 16 + ln) * 32 + q4 * 8);
    for (int ct = 0; ct < 4; ++ct) {
      int brow = (wc * 64 + ct * 16 + ln) * 32 + q4 * 8;
      short8 b0 = *(const short8*)(SB + 2 * 4096 + brow);
      short8 b1 = *(const short8*)(SB + 3 * 4096 + brow);
      for (int mt = 0; mt < 4; ++mt) {
        float4v a = acc[mt][ct];
        a = mfma16(af[mt][0], b0, a);
        a = mfma16(af[mt][1], b0, a);
        a = mfma16(af[mt][0], b1, a);
        acc[mt][ct] = a;
      }
    }
  }

  for (int mt = 0; mt < 4; ++mt)
    for (int ct = 0; ct < 4; ++ct)
      for (int r = 0; r < 4; ++r) {
        int gm = m0 + wr * 64 + mt * 16 + q4 * 4 + r;
        int col = n0g + wc * 64 + ct * 16 + ln;
        out[(size_t)gm * D_MODEL + col] = acc[mt][ct][r];
      }
}

extern "C" void kernel_launch(void* const* d_in, const int* in_sizes, int n_in,
                              void* d_out, int out_size, void* d_ws, size_t ws_size,
                              hipStream_t stream) {
  const float* x      = (const float*)d_in[0];
  const float* ln_w   = (const float*)d_in[1];
  const float* attn_w = (const float*)d_in[2];
  const float* proj_w = (const float*)d_in[3];
  const float* theta  = (const float*)d_in[4];
  float* out = (float*)d_out;

  char* ws = (char*)d_ws;
  const size_t SZY  = (size_t)4096 * 1024 * 2;        // 8,388,608
  const size_t SZW  = (size_t)3072 * 1024 * 2;        // 6,291,456
  const size_t SZW2 = (size_t)2048 * 1024 * 2;        // 4,194,304
  const size_t SZQ  = (size_t)2 * 16 * 2048 * 64 * 4; // 16,777,216 (fp32)
  const size_t SZK  = (size_t)2 * 16 * 2048 * 64 * 2; //  8,388,608 (bf16)

  unsigned short* y0 = (unsigned short*)(ws);
  unsigned short* y1 = (unsigned short*)(ws + SZY);
  unsigned short* y2 = (unsigned short*)(ws + 2 * SZY);
  unsigned short* W0 = (unsigned short*)(ws + 3 * SZY);
  unsigned short* W1 = (unsigned short*)(ws + 3 * SZY + SZW);
  unsigned short* W2 = (unsigned short*)(ws + 3 * SZY + 2 * SZW);
  float* Qf          = (float*)(ws + 3 * SZY + 2 * SZW + SZW2);
  unsigned short* K0 = (unsigned short*)(ws + 3 * SZY + 2 * SZW + SZW2 + SZQ);
  unsigned short* K1 = (unsigned short*)(ws + 3 * SZY + 2 * SZW + SZW2 + SZQ + SZK);
  float* E           = (float*)(ws + 3 * SZY + 2 * SZW + SZW2 + SZQ + 2 * SZK);
  float* Einv        = E + T_SEQ;
  // aliases into dead regions (y dead after qkv_*, then reused):
  unsigned short* Ob0 = y0;
  unsigned short* Ob1 = y1;
  unsigned short* PW0 = y2;
  unsigned short* PW1 = y2 + (size_t)1024 * 1024;
  // d_out scratch (16.78 MB): VbT low half, K2 high half; both dead before proj writes
  unsigned short* VbT = (unsigned short*)d_out;
  unsigned short* K2  = (unsigned short*)((char*)d_out + SZK);

  size_t needed = 3 * SZY + 2 * SZW + SZW2 + SZQ + 2 * SZK + 2 * T_SEQ * 4;  // 75,513,856
  if (ws_size < needed) return;  // loud failure: output stays zero

  eta_kernel<<<dim3(8), dim3(256), 0, stream>>>(theta, E, Einv);
  ln_kernel<<<dim3(4096), dim3(256), 0, stream>>>(x, ln_w, y0, y1, y2);
  conv_w3<<<dim3(1536), dim3(256), 0, stream>>>(attn_w, W0, W1, W2);
  qkv_qk<<<dim3(16, 32), dim3(256), 0, stream>>>(y0, y1, y2, W0, W1, W2, E, Einv,
                                                 Qf, K0, K1, K2);
  qkv_v<<<dim3(8, 32), dim3(256), 0, stream>>>(y0, y1, W0, W1, VbT);
  attn_kernel<<<dim3(16, 32), dim3(256), 0, stream>>>(Qf, K0, K1, K2, VbT, Ob0, Ob1);
  conv_pw<<<dim3(512), dim3(256), 0, stream>>>(proj_w, PW0, PW1);
  proj_gemm<<<dim3(8, 32), dim3(256), 0, stream>>>(Ob0, Ob1, PW0, PW1, out);
}

// Round 10
// 375.283 us; speedup vs baseline: 4.0166x; 1.0175x over previous
//
#include <hip/hip_runtime.h>
#include <stdint.h>
#include <stddef.h>

typedef __attribute__((ext_vector_type(8))) short short8;
typedef __attribute__((ext_vector_type(4))) float float4v;

#define T_SEQ 2048
#define D_MODEL 1024
#define NH 16
#define HD 64

static __device__ __forceinline__ unsigned short f2bf(float f) {
  unsigned u = __builtin_bit_cast(unsigned, f);
  u += 0x7fffu + ((u >> 16) & 1u);
  return (unsigned short)(u >> 16);
}
static __device__ __forceinline__ float bf2f(unsigned short h) {
  unsigned u = ((unsigned)h) << 16;
  return __builtin_bit_cast(float, u);
}
static __device__ __forceinline__ float4v mfma16(short8 a, short8 b, float4v c) {
  return __builtin_amdgcn_mfma_f32_16x16x32_bf16(a, b, c, 0, 0, 0);
}
// fp32 -> 3 bf16 terms (sum reproduces f to ~2^-27 rel)
static __device__ __forceinline__ void split3(float f, unsigned short& h0,
                                              unsigned short& h1, unsigned short& h2) {
  h0 = f2bf(f);
  float r1 = f - bf2f(h0);
  h1 = f2bf(r1);
  float r2 = r1 - bf2f(h1);
  h2 = f2bf(r2);
}
// fp32 -> 2 bf16 terms (~2^-18 rel)
static __device__ __forceinline__ void split2(float f, unsigned short& h0, unsigned short& h1) {
  h0 = f2bf(f);
  h1 = f2bf(f - bf2f(h0));
}

// async global->LDS, 16 B per lane (global_load_lds_dwordx4); guarded fallback
static __device__ __forceinline__ void stage16(const unsigned short* g, unsigned short* l) {
#if __has_builtin(__builtin_amdgcn_global_load_lds)
  __builtin_amdgcn_global_load_lds(
      (const __attribute__((address_space(1))) unsigned int*)g,
      (__attribute__((address_space(3))) unsigned int*)l, 16, 0, 0);
#else
  *(short8*)l = *(const short8*)g;
#endif
}

// ---------------- prep: eta tables + LayerNorm split3 + attn_w split3 ----------------
__global__ __launch_bounds__(256) void prep_kernel(
    const float* x, const float* wgt, const float* attn_w, const float* theta,
    unsigned short* y0, unsigned short* y1, unsigned short* y2,
    unsigned short* W0, unsigned short* W1, unsigned short* W2,
    float* E, float* Einv) {
  __shared__ float rs[4], rq[4];
  int bx = blockIdx.x;
  int tid = threadIdx.x;
  if (bx < 4096) {                       // ---- LayerNorm rows ----
    int row = bx;
    const float* xr = x + (size_t)row * D_MODEL;
    float v[4];
    float sum = 0.f, ssq = 0.f;
    for (int it = 0; it < 4; ++it) {
      float f = xr[tid + 256 * it];
      v[it] = f;
      sum += f; ssq += f * f;
    }
    for (int off = 32; off >= 1; off >>= 1) {
      sum += __shfl_xor(sum, off, 64);
      ssq += __shfl_xor(ssq, off, 64);
    }
    int w = tid >> 6;
    if ((tid & 63) == 0) { rs[w] = sum; rq[w] = ssq; }
    __syncthreads();
    sum = rs[0] + rs[1] + rs[2] + rs[3];
    ssq = rq[0] + rq[1] + rq[2] + rq[3];
    float mu = sum * (1.0f / D_MODEL);
    float var = ssq * (1.0f / D_MODEL) - mu * mu;
    float rstd = rsqrtf(var + 1e-5f);
    for (int it = 0; it < 4; ++it) {
      int d = tid + 256 * it;
      float y = (v[it] - mu) * rstd * wgt[d];
      unsigned short h0, h1, h2;
      split3(y, h0, h1, h2);
      size_t o = (size_t)row * D_MODEL + d;
      y0[o] = h0; y1[o] = h1; y2[o] = h2;
    }
  } else if (bx < 5632) {                // ---- attn_w split3 ----
    size_t base = ((size_t)(bx - 4096) * 256 + tid) * 8;
    int row = (int)(base >> 10);
    short8 a, b, c;
    for (int j = 0; j < 8; ++j) {
      unsigned short h0, h1, h2;
      split3(attn_w[base + j], h0, h1, h2);
      a[j] = (short)h0; b[j] = (short)h1; c[j] = (short)h2;
    }
    *(short8*)(W0 + base) = a;
    *(short8*)(W1 + base) = b;
    if (row < 2048) *(short8*)(W2 + base) = c;
  } else {                               // ---- eta tables ----
    int i = (bx - 5632) * 256 + tid;
    if (i < T_SEQ) {
      float th = theta[0];
      float h = log1pf(expf(th));
      float t = 1.0f + h * (float)i;
      float eta = 3.0f * logf(t);
      eta = fminf(fmaxf(eta, -50.0f), 50.0f);
      E[i] = expf(eta);
      Einv[i] = expf(-eta);
    }
  }
}

// ---------------- proj_w (fp32) -> split2 ----------------
__global__ __launch_bounds__(256) void conv_pw(const float* src, unsigned short* P0,
                                               unsigned short* P1) {
  size_t base = ((size_t)blockIdx.x * 256 + threadIdx.x) * 8;
  short8 a, b;
  for (int j = 0; j < 8; ++j) {
    unsigned short h0, h1;
    split2(src[base + j], h0, h1);
    a[j] = (short)h0; b[j] = (short)h1;
  }
  *(short8*)(P0 + base) = a;
  *(short8*)(P1 + base) = b;
}

// ---------------- merged QKV GEMM (x<16: Q/K 6-term; x>=16: V 3-term) ----------------
__global__ __launch_bounds__(256) void qkv_gemm(
    const unsigned short* y0, const unsigned short* y1, const unsigned short* y2,
    const unsigned short* W0, const unsigned short* W1, const unsigned short* W2,
    const float* E, const float* Einv,
    float* Qf, unsigned short* K0, unsigned short* K1, unsigned short* K2,
    unsigned short* VbT) {
  __shared__ unsigned short SB[6 * 4096];   // 48 KB
  int tid = threadIdx.x;
  int w = tid >> 6, lane = tid & 63, q4 = lane >> 4, ln = lane & 15;
  int wr = w >> 1, wc = w & 1;
  int m0 = blockIdx.y * 128;
  int bi = m0 >> 11;
  int m0g = m0 & 2047;
  int srow = tid >> 2, kpart = tid & 3;
  unsigned lds_off = (unsigned)tid * 16;
  float4v zero = {0.f, 0.f, 0.f, 0.f};
  float4v acc[4][4];
  for (int mt = 0; mt < 4; ++mt)
    for (int ct = 0; ct < 4; ++ct) acc[mt][ct] = zero;

  if (blockIdx.x < 16) {
    // ======== Q/K region: 6-term split ========
    int n0g = blockIdx.x * 128;
    const unsigned short* Asrc[3] = {y0, y1, y2};
    const unsigned short* Bsrc[3] = {W0, W1, W2};
    for (int k0 = 0; k0 < D_MODEL; k0 += 32) {
      __syncthreads();
      for (int i = 0; i < 2; ++i) {
        size_t arow = (size_t)(m0 + srow + i * 64) * D_MODEL + k0 + kpart * 8;
        size_t brow = (size_t)(n0g + srow + i * 64) * D_MODEL + k0 + kpart * 8;
        for (int s = 0; s < 3; ++s) {
          stage16(Asrc[s] + arow, (unsigned short*)((char*)(SB + s * 4096) + lds_off + i * 4096));
          stage16(Bsrc[s] + brow, (unsigned short*)((char*)(SB + (3 + s) * 4096) + lds_off + i * 4096));
        }
      }
      __syncthreads();
      short8 af[4][3];
      for (int mt = 0; mt < 4; ++mt)
        for (int s = 0; s < 3; ++s)
          af[mt][s] = *(const short8*)(SB + s * 4096 + (wr * 64 + mt * 16 + ln) * 32 + q4 * 8);
      for (int ct = 0; ct < 4; ++ct) {
        int brow = (wc * 64 + ct * 16 + ln) * 32 + q4 * 8;
        short8 b0 = *(const short8*)(SB + 3 * 4096 + brow);
        short8 b1 = *(const short8*)(SB + 4 * 4096 + brow);
        short8 b2 = *(const short8*)(SB + 5 * 4096 + brow);
        for (int mt = 0; mt < 4; ++mt) {
          float4v a = acc[mt][ct];
          a = mfma16(af[mt][0], b0, a);
          a = mfma16(af[mt][1], b0, a);
          a = mfma16(af[mt][0], b1, a);
          a = mfma16(af[mt][1], b1, a);
          a = mfma16(af[mt][0], b2, a);
          a = mfma16(af[mt][2], b0, a);
          acc[mt][ct] = a;
        }
      }
    }
    int region = n0g >> 10;            // 0=Q 1=K
    __syncthreads();
    if (region == 0) {
      float* Ql = (float*)SB;          // [128][64] fp32
      for (int h = 0; h < 2; ++h) {
        if (wc == h) {
          for (int mt = 0; mt < 4; ++mt)
            for (int ct = 0; ct < 4; ++ct)
              for (int r = 0; r < 4; ++r) {
                int t_loc = wr * 64 + mt * 16 + q4 * 4 + r;
                int d = ct * 16 + ln;
                int t = m0g + t_loc;
                Ql[t_loc * 64 + d] = acc[mt][ct][r] * (E[t] * 0.1803368801f); // 0.125*log2e
              }
        }
        __syncthreads();
        int h_glob = ((n0g + h * 64) & 1023) >> 6;
        float* dst = Qf + ((size_t)(bi * NH + h_glob) * T_SEQ + m0g) * HD;
        for (int it = 0; it < 8; ++it) {
          int idx = it * 256 + tid;
          *(float4v*)(dst + idx * 4) = *(const float4v*)(Ql + idx * 4);
        }
        __syncthreads();
      }
    } else {
      unsigned short* Kl = SB;         // [3][128][64] bf16
      for (int h = 0; h < 2; ++h) {
        if (wc == h) {
          for (int mt = 0; mt < 4; ++mt)
            for (int ct = 0; ct < 4; ++ct)
              for (int r = 0; r < 4; ++r) {
                int t_loc = wr * 64 + mt * 16 + q4 * 4 + r;
                int d = ct * 16 + ln;
                int t = m0g + t_loc;
                unsigned short h0, h1, h2;
                split3(acc[mt][ct][r] * Einv[t], h0, h1, h2);
                Kl[t_loc * 64 + d] = h0;
                Kl[8192 + t_loc * 64 + d] = h1;
                Kl[16384 + t_loc * 64 + d] = h2;
              }
        }
        __syncthreads();
        int h_glob = ((n0g + h * 64) & 1023) >> 6;
        size_t base = ((size_t)(bi * NH + h_glob) * T_SEQ + m0g) * HD;
        unsigned short* dsts[3] = {K0 + base, K1 + base, K2 + base};
        for (int s = 0; s < 3; ++s)
          for (int it = 0; it < 4; ++it) {
            int idx = it * 256 + tid;
            *(short8*)(dsts[s] + idx * 8) = *(const short8*)(Kl + s * 8192 + idx * 8);
          }
        __syncthreads();
      }
    }
  } else {
    // ======== V region: 3-term split, transposed [b,h,d,t] write ========
    int n0g = (blockIdx.x - 16) * 128;
    const unsigned short* Asrc[2] = {y0, y1};
    const unsigned short* Bsrc[2] = {W0, W1};
    for (int k0 = 0; k0 < D_MODEL; k0 += 32) {
      __syncthreads();
      for (int i = 0; i < 2; ++i) {
        size_t arow = (size_t)(m0 + srow + i * 64) * D_MODEL + k0 + kpart * 8;
        size_t brow = (size_t)(2048 + n0g + srow + i * 64) * D_MODEL + k0 + kpart * 8;
        for (int s = 0; s < 2; ++s) {
          stage16(Asrc[s] + arow, (unsigned short*)((char*)(SB + s * 4096) + lds_off + i * 4096));
          stage16(Bsrc[s] + brow, (unsigned short*)((char*)(SB + (2 + s) * 4096) + lds_off + i * 4096));
        }
      }
      __syncthreads();
      short8 af[4][2];
      for (int mt = 0; mt < 4; ++mt)
        for (int s = 0; s < 2; ++s)
          af[mt][s] = *(const short8*)(SB + s * 4096 + (wr * 64 + mt * 16 + ln) * 32 + q4 * 8);
      for (int ct = 0; ct < 4; ++ct) {
        int brow = (wc * 64 + ct * 16 + ln) * 32 + q4 * 8;
        short8 b0 = *(const short8*)(SB + 2 * 4096 + brow);
        short8 b1 = *(const short8*)(SB + 3 * 4096 + brow);
        for (int mt = 0; mt < 4; ++mt) {
          float4v a = acc[mt][ct];
          a = mfma16(af[mt][0], b0, a);
          a = mfma16(af[mt][1], b0, a);
          a = mfma16(af[mt][0], b1, a);
          acc[mt][ct] = a;
        }
      }
    }
    __syncthreads();
    unsigned short* Vl = SB;           // [64][128] bf16
    for (int h = 0; h < 2; ++h) {
      if (wc == h) {
        for (int mt = 0; mt < 4; ++mt)
          for (int ct = 0; ct < 4; ++ct)
            for (int r = 0; r < 4; ++r) {
              int t_loc = wr * 64 + mt * 16 + q4 * 4 + r;
              int d = ct * 16 + ln;
              Vl[d * 128 + t_loc] = f2bf(acc[mt][ct][r]);
            }
      }
      __syncthreads();
      int h_glob = (n0g + h * 64) >> 6;
      size_t base = (size_t)(bi * NH + h_glob) * HD * T_SEQ + m0g;
      for (int it = 0; it < 4; ++it) {
        int idx = it * 256 + tid;
        int d = idx >> 4, c = idx & 15;
        *(short8*)(VbT + base + (size_t)d * T_SEQ + c * 8) =
            *(const short8*)(Vl + d * 128 + c * 8);
      }
      __syncthreads();
    }
  }
}

// ---------------- fused causal attention ----------------
// 1-D grid with XCD-locality swizzle: all 16 px-blocks of a bh land on one XCD
// (bidx%8 = bh>>2) so its K/V stream is fetched into that XCD's L2 once.
// Diagonal tile hoisted out of jt loop (mask code only there); P transpose uses
// truncating bf16 (1 VALU op); l from ones-MFMA stays consistent with stored P.
#define ATTN_STAGE(BUF, J0)                                                   \
  for (int i_ = 0; i_ < 2; ++i_) {                                            \
    size_t go_ = (size_t)((J0) + srow + i_ * 32) * 64 + scd * 8;              \
    int lo_ = tid * 8 + i_ * 2048;                                            \
    stage16(Kb0 + go_, &Ks[BUF][0][lo_]);                                     \
    stage16(Kb1 + go_, &Ks[BUF][1][lo_]);                                     \
    stage16(Kb2 + go_, &Ks[BUF][2][lo_]);                                     \
    stage16(Vb + (size_t)(srow + i_ * 32) * T_SEQ + (J0) + scd * 8,           \
            &Vs[BUF][lo_]);                                                   \
  }

#define ATTN_STEP(JT, DIAG)                                                   \
  {                                                                           \
    const int cur_ = (JT) & 1;                                                \
    float p[4][4];                                                            \
    for (int c = 0; c < 4; ++c) {                                             \
      float4v s = zero;                                                       \
      for (int ks = 0; ks < 2; ++ks) {                                        \
        int koff = ((c * 16 + ln) * 8 + ((ks * 4 + q4) ^ swz)) * 8;           \
        short8 k0v = *(const short8*)&Ks[cur_][0][koff];                      \
        short8 k1v = *(const short8*)&Ks[cur_][1][koff];                      \
        short8 k2v = *(const short8*)&Ks[cur_][2][koff];                      \
        s = mfma16(qa[ks][0], k0v, s);                                        \
        s = mfma16(qa[ks][1], k0v, s);                                        \
        s = mfma16(qa[ks][0], k1v, s);                                        \
        s = mfma16(qa[ks][1], k1v, s);                                        \
        s = mfma16(qa[ks][0], k2v, s);                                        \
        s = mfma16(qa[ks][2], k0v, s);                                        \
      }                                                                       \
      if (DIAG) {                                                             \
        int jrow = (JT) * 64 + c * 16 + ln;                                   \
        for (int r = 0; r < 4; ++r)                                           \
          if (jrow > ibase + q4 * 4 + r) s[r] = -3e38f;                       \
      }                                                                       \
      for (int r = 0; r < 4; ++r) p[c][r] = s[r];                             \
    }                                                                         \
    float alpha[4], mnew[4];                                                  \
    for (int r = 0; r < 4; ++r) {                                             \
      float tm = fmaxf(fmaxf(p[0][r], p[1][r]), fmaxf(p[2][r], p[3][r]));     \
      for (int off = 8; off >= 1; off >>= 1)                                  \
        tm = fmaxf(tm, __shfl_xor(tm, off, 16));                              \
      mnew[r] = fmaxf(m_r[r], tm);                                            \
      alpha[r] = exp2f(m_r[r] - mnew[r]);                                     \
      m_r[r] = mnew[r];                                                       \
    }                                                                         \
    for (int c = 0; c < 4; ++c)                                               \
      for (int r = 0; r < 4; ++r) p[c][r] = exp2f(p[c][r] - mnew[r]);         \
    for (int c = 0; c < 4; ++c)                                               \
      for (int r = 0; r < 4; ++r) oacc[c][r] *= alpha[r];                     \
    for (int r = 0; r < 4; ++r) lacc[r] *= alpha[r];                          \
    __asm__ __volatile__("" ::: "memory");                                    \
    for (int c = 0; c < 4; ++c)                                               \
      for (int r = 0; r < 4; ++r)                                             \
        Plds[w][q4 * 4 + r][c * 16 + ln] =                                    \
            (unsigned short)(__builtin_bit_cast(unsigned, p[c][r]) >> 16);    \
    __asm__ __volatile__("" ::: "memory");                                    \
    for (int ks = 0; ks < 2; ++ks) {                                          \
      short8 pa = *(const short8*)&Plds[w][ln][ks * 32 + q4 * 8];             \
      for (int c = 0; c < 4; ++c) {                                           \
        int voff = ((c * 16 + ln) * 8 + ((ks * 4 + q4) ^ swz)) * 8;           \
        short8 vb = *(const short8*)&Vs[cur_][voff];                          \
        oacc[c] = mfma16(pa, vb, oacc[c]);                                    \
      }                                                                       \
      lacc = mfma16(pa, ones, lacc);                                          \
    }                                                                         \
    __asm__ __volatile__("" ::: "memory");                                    \
  }

__global__ __launch_bounds__(256) void attn_kernel(
    const float* Qf, const unsigned short* K0, const unsigned short* K1,
    const unsigned short* K2, const unsigned short* VbT,
    unsigned short* Ob0, unsigned short* Ob1) {
  __shared__ unsigned short Ks[2][3][4096];
  __shared__ unsigned short Vs[2][4096];
  __shared__ unsigned short Plds[4][16][72];
  int tid = threadIdx.x;
  int w = tid >> 6, lane = tid & 63, q4 = lane >> 4, ln = lane & 15;
  int bidx = blockIdx.x;                       // 0..511
  int bh = ((bidx & 7) << 2) | ((bidx >> 3) & 3);   // XCD swizzle
  int px = bidx >> 5;                          // 0..15 -> pair (px, 31-px)
  const float* Qb = Qf + (size_t)bh * T_SEQ * HD;
  const unsigned short* Kb0 = K0 + (size_t)bh * T_SEQ * HD;
  const unsigned short* Kb1 = K1 + (size_t)bh * T_SEQ * HD;
  const unsigned short* Kb2 = K2 + (size_t)bh * T_SEQ * HD;
  const unsigned short* Vb = VbT + (size_t)bh * HD * T_SEQ;
  int b = bh >> 4, hh = bh & 15;
  float4v zero = {0.f, 0.f, 0.f, 0.f};
  short8 ones;
  for (int j = 0; j < 8; ++j) ones[j] = (short)(unsigned short)0x3F80;  // bf16 1.0

  int srow = tid >> 3, scs = tid & 7;
  int scd = scs ^ (srow & 7);
  int swz = ln & 7;

  for (int half = 0; half < 2; ++half) {
    int qt = half ? (31 - px) : px;
    int q0 = qt * 64;
    int ibase = q0 + w * 16;

    short8 qa[2][3];
    {
      const float* qp = Qb + (size_t)(ibase + ln) * HD;
      for (int ks = 0; ks < 2; ++ks) {
        float f[8];
        *(float4v*)&f[0] = *(const float4v*)(qp + ks * 32 + q4 * 8);
        *(float4v*)&f[4] = *(const float4v*)(qp + ks * 32 + q4 * 8 + 4);
        for (int j = 0; j < 8; ++j) {
          unsigned short h0, h1, h2;
          split3(f[j], h0, h1, h2);
          qa[ks][0][j] = (short)h0; qa[ks][1][j] = (short)h1; qa[ks][2][j] = (short)h2;
        }
      }
    }

    float m_r[4] = {-3e38f, -3e38f, -3e38f, -3e38f};
    float4v lacc = zero;
    float4v oacc[4];
    for (int c = 0; c < 4; ++c) oacc[c] = zero;

    __syncthreads();           // previous half's reads drained
    ATTN_STAGE(0, 0)
    for (int jt = 0; jt < qt; ++jt) {
      __syncthreads();         // tile jt staged; reads of other buf drained
      ATTN_STAGE((jt + 1) & 1, (jt + 1) * 64)
      ATTN_STEP(jt, 0)
    }
    __syncthreads();           // diagonal tile staged
    ATTN_STEP(qt, 1)

    for (int c = 0; c < 4; ++c)
      for (int r = 0; r < 4; ++r) {
        int i = ibase + q4 * 4 + r;
        float val = oacc[c][r] / lacc[r];
        unsigned short h0, h1;
        split2(val, h0, h1);
        size_t o = ((size_t)(b * T_SEQ + i)) * D_MODEL + hh * 64 + c * 16 + ln;
        Ob0[o] = h0; Ob1[o] = h1;
      }
  }
}
#undef ATTN_STAGE
#undef ATTN_STEP

// ---------------- output projection: LDS-staged, 3-term, fp32 out ----------------
__global__ __launch_bounds__(256) void proj_gemm(
    const unsigned short* A0, const unsigned short* A1,
    const unsigned short* P0, const unsigned short* P1, float* out) {
  __shared__ unsigned short SB[4 * 4096];
  int tid = threadIdx.x;
  int w = tid >> 6, lane = tid & 63, q4 = lane >> 4, ln = lane & 15;
  int wr = w >> 1, wc = w & 1;
  int n0g = blockIdx.x * 128;
  int m0 = blockIdx.y * 128;
  const unsigned short* Asrc[2] = {A0, A1};
  const unsigned short* Bsrc[2] = {P0, P1};

  float4v zero = {0.f, 0.f, 0.f, 0.f};
  float4v acc[4][4];
  for (int mt = 0; mt < 4; ++mt)
    for (int ct = 0; ct < 4; ++ct) acc[mt][ct] = zero;

  int srow = tid >> 2, kpart = tid & 3;
  unsigned lds_off = (unsigned)tid * 16;

  for (int k0 = 0; k0 < D_MODEL; k0 += 32) {
    __syncthreads();
    for (int i = 0; i < 2; ++i) {
      size_t arow = (size_t)(m0 + srow + i * 64) * D_MODEL + k0 + kpart * 8;
      size_t brow = (size_t)(n0g + srow + i * 64) * D_MODEL + k0 + kpart * 8;
      for (int s = 0; s < 2; ++s) {
        stage16(Asrc[s] + arow, (unsigned short*)((char*)(SB + s * 4096) + lds_off + i * 4096));
        stage16(Bsrc[s] + brow, (unsigned short*)((char*)(SB + (2 + s) * 4096) + lds_off + i * 4096));
      }
    }
    __syncthreads();

    short8 af[4][2];
    for (int mt = 0; mt < 4; ++mt)
      for (int s = 0; s < 2; ++s)
        af[mt][s] = *(const short8*)(SB + s * 4096 + (wr * 64 + mt * 16 + ln) * 32 + q4 * 8);
    for (int ct = 0; ct < 4; ++ct) {
      int brow = (wc * 64 + ct * 16 + ln) * 32 + q4 * 8;
      short8 b0 = *(const short8*)(SB + 2 * 4096 + brow);
      short8 b1 = *(const short8*)(SB + 3 * 4096 + brow);
      for (int mt = 0; mt < 4; ++mt) {
        float4v a = acc[mt][ct];
        a = mfma16(af[mt][0], b0, a);
        a = mfma16(af[mt][1], b0, a);
        a = mfma16(af[mt][0], b1, a);
        acc[mt][ct] = a;
      }
    }
  }

  for (int mt = 0; mt < 4; ++mt)
    for (int ct = 0; ct < 4; ++ct)
      for (int r = 0; r < 4; ++r) {
        int gm = m0 + wr * 64 + mt * 16 + q4 * 4 + r;
        int col = n0g + wc * 64 + ct * 16 + ln;
        out[(size_t)gm * D_MODEL + col] = acc[mt][ct][r];
      }
}

extern "C" void kernel_launch(void* const* d_in, const int* in_sizes, int n_in,
                              void* d_out, int out_size, void* d_ws, size_t ws_size,
                              hipStream_t stream) {
  const float* x      = (const float*)d_in[0];
  const float* ln_w   = (const float*)d_in[1];
  const float* attn_w = (const float*)d_in[2];
  const float* proj_w = (const float*)d_in[3];
  const float* theta  = (const float*)d_in[4];
  float* out = (float*)d_out;

  char* ws = (char*)d_ws;
  const size_t SZY  = (size_t)4096 * 1024 * 2;        // 8,388,608
  const size_t SZW  = (size_t)3072 * 1024 * 2;        // 6,291,456
  const size_t SZW2 = (size_t)2048 * 1024 * 2;        // 4,194,304
  const size_t SZQ  = (size_t)2 * 16 * 2048 * 64 * 4; // 16,777,216 (fp32)
  const size_t SZK  = (size_t)2 * 16 * 2048 * 64 * 2; //  8,388,608 (bf16)

  unsigned short* y0 = (unsigned short*)(ws);
  unsigned short* y1 = (unsigned short*)(ws + SZY);
  unsigned short* y2 = (unsigned short*)(ws + 2 * SZY);
  unsigned short* W0 = (unsigned short*)(ws + 3 * SZY);
  unsigned short* W1 = (unsigned short*)(ws + 3 * SZY + SZW);
  unsigned short* W2 = (unsigned short*)(ws + 3 * SZY + 2 * SZW);
  float* Qf          = (float*)(ws + 3 * SZY + 2 * SZW + SZW2);
  unsigned short* K0 = (unsigned short*)(ws + 3 * SZY + 2 * SZW + SZW2 + SZQ);
  unsigned short* K1 = (unsigned short*)(ws + 3 * SZY + 2 * SZW + SZW2 + SZQ + SZK);
  float* E           = (float*)(ws + 3 * SZY + 2 * SZW + SZW2 + SZQ + 2 * SZK);
  float* Einv        = E + T_SEQ;
  // aliases into dead regions (y dead after qkv, then reused):
  unsigned short* Ob0 = y0;
  unsigned short* Ob1 = y1;
  unsigned short* PW0 = y2;
  unsigned short* PW1 = y2 + (size_t)1024 * 1024;
  // d_out scratch (16.78 MB): VbT low half, K2 high half; both dead before proj writes
  unsigned short* VbT = (unsigned short*)d_out;
  unsigned short* K2  = (unsigned short*)((char*)d_out + SZK);

  size_t needed = 3 * SZY + 2 * SZW + SZW2 + SZQ + 2 * SZK + 2 * T_SEQ * 4;  // 75,513,856
  if (ws_size < needed) return;  // loud failure: output stays zero

  prep_kernel<<<dim3(5640), dim3(256), 0, stream>>>(x, ln_w, attn_w, theta,
                                                    y0, y1, y2, W0, W1, W2, E, Einv);
  qkv_gemm<<<dim3(24, 32), dim3(256), 0, stream>>>(y0, y1, y2, W0, W1, W2, E, Einv,
                                                   Qf, K0, K1, K2, VbT);
  conv_pw<<<dim3(512), dim3(256), 0, stream>>>(proj_w, PW0, PW1);
  attn_kernel<<<dim3(512), dim3(256), 0, stream>>>(Qf, K0, K1, K2, VbT, Ob0, Ob1);
  proj_gemm<<<dim3(8, 32), dim3(256), 0, stream>>>(Ob0, Ob1, PW0, PW1, out);
}